// Round 9
// baseline (89.683 us; speedup 1.0000x reference)
//
#include <hip/hip_runtime.h>
#include <stdint.h>

// MPS amplitude via MFMA, round 9: barrier-free register-resident chain.
// GEMM per site: C[j(32 rows, 2 mt-tiles)][e(16 cols)] = sum_k A^[j][k]*V[k][e].
// Elements are the N dim -> lane's col (l&15) = its element all chain long.
// K-relabeling beta baked into preconverted ws so site t's C accumulator regs
// ARE site t+1's B-operand words: no LDS, no barriers, no cross-lane moves.
// Per wave: 16 elements, both spins computed (48 MFMA/site), per-lane
// cndmask spin select, cvt_pk bf16 hi/lo split repack (3-term split GEMM).
// 256 blocks x 128 thr (2 waves/CU, A-frags shared via L1). ws = 992KB, L2.

typedef __attribute__((ext_vector_type(4))) float        f32x4;
typedef __attribute__((ext_vector_type(8))) short        s16x8;
typedef __attribute__((ext_vector_type(4))) unsigned int u32x4;

__device__ __forceinline__ unsigned cvt_pk_bf16(float lo, float hi) {
    unsigned r;
    asm("v_cvt_pk_bf16_f32 %0, %1, %2" : "=v"(r) : "v"(lo), "v"(hi));
    return r;
}
__device__ __forceinline__ float lo_f(unsigned h) { return __uint_as_float(h << 16); }
__device__ __forceinline__ float hi_f(unsigned h) { return __uint_as_float(h & 0xFFFF0000u); }
__device__ __forceinline__ s16x8 frg(u32x4 x) { return __builtin_bit_cast(s16x8, x); }
#define MFMA16(A, B, C) __builtin_amdgcn_mfma_f32_16x16x32_bf16(frg(A), frg(B), C, 0, 0, 0)

// ws layout (u32 words), per site (stride 4096):
//   W = s*1024 + mt*512 + kk*256 + jlr*16 + lg*4 + q   (0..2047)
//   hi word at site*4096 + W ; lo word at site*4096 + 2048 + W
//   word = pack(Ar[i][j], Ai[i][j]),  i = kk*16 + 4*lg + q,  j = mt*16 + jlr
// This realizes beta: A-frag word q of lane (jlr,lg) covers k-pair
// (2w,2w+1) with w = kk*16 + [2lg,2lg+1,8+2lg,8+2lg+1][q].
__global__ __launch_bounds__(256, 1) void mps_preconvert(
    const float* __restrict__ bulk_r, const float* __restrict__ bulk_i,
    unsigned* __restrict__ ws)
{
    const int site = blockIdx.x;          // 0..61
    const int tid  = threadIdx.x;
    unsigned* wsu = ws + (size_t)site * 4096;
    const float* br = bulk_r + (size_t)site * 2048;
    const float* bi = bulk_i + (size_t)site * 2048;
    #pragma unroll
    for (int k = 0; k < 8; ++k) {
        const int W   = tid + k * 256;
        const int s   = W >> 10;
        const int mt  = (W >> 9) & 1;
        const int kk  = (W >> 8) & 1;
        const int jlr = (W >> 4) & 15;
        const int lg  = (W >> 2) & 3;
        const int q   = W & 3;
        const int i   = kk * 16 + 4 * lg + q;
        const int j   = mt * 16 + jlr;
        const float ar = br[s * 1024 + i * 32 + j];
        const float ai = bi[s * 1024 + i * 32 + j];
        const unsigned h  = cvt_pk_bf16(ar, ai);
        const unsigned lo = cvt_pk_bf16(ar - lo_f(h), ai - hi_f(h));
        wsu[W]        = h;
        wsu[2048 + W] = lo;
    }
}

__global__ __launch_bounds__(128, 1) void mps_chain_kernel(
    const int*   __restrict__ spin,
    const float* __restrict__ left_r,  const float* __restrict__ left_i,
    const float* __restrict__ right_r, const float* __restrict__ right_i,
    const unsigned* __restrict__ ws,
    float2*      __restrict__ out)
{
    __shared__ unsigned smask[32][2];

    const int tid = threadIdx.x;
    const int l   = tid & 63;
    const int wv  = tid >> 6;            // wave 0..1
    const int el  = l & 15;              // element within wave = C column
    const int lg  = l >> 4;              // k-group / row-group
    const int blk = blockIdx.x;
    const int eg  = blk * 32 + wv * 16 + el;

    // ---- spin masks (one barrier, prologue only) ----
    if (tid < 32) {
        const int* sp = spin + (size_t)(blk * 32 + tid) * 64;
        unsigned a0 = 0, a1 = 0;
        #pragma unroll
        for (int k = 0; k < 32; ++k) a0 |= (unsigned)(sp[k] & 1) << k;
        #pragma unroll
        for (int k = 0; k < 32; ++k) a1 |= (unsigned)(sp[32 + k] & 1) << k;
        smask[tid][0] = a0; smask[tid][1] = a1;
    }
    __syncthreads();
    const unsigned em0 = smask[wv * 16 + el][0];
    const unsigned em1 = smask[wv * 16 + el][1];

    // ---- v state as B-operand frags: Bh[kk], Bl[kk] (kk = K 32-chunk) ----
    u32x4 Bh[2], Bl[2];
    {
        const int s0 = (int)(em0 & 1u);
        #pragma unroll
        for (int kk = 0; kk < 2; ++kk)
            #pragma unroll
            for (int q = 0; q < 4; ++q) {
                const int i = kk * 16 + 4 * lg + q;
                const float vr = left_r[s0 * 32 + i];
                const float vi = left_i[s0 * 32 + i];
                const unsigned h = cvt_pk_bf16(vr, vi);
                Bh[kk][q] = h;
                Bl[kk][q] = cvt_pk_bf16(vr - lo_f(h), vi - hi_f(h));
            }
    }

    const int voffw = el * 16 + lg * 4;   // per-lane A-frag word offset

    // A-frag double buffer: [s][mt][kk][hl]
    u32x4 A0[2][2][2][2], A1[2][2][2][2];
    {
        const unsigned* p = ws + voffw;
        #pragma unroll
        for (int s = 0; s < 2; ++s)
            #pragma unroll
            for (int mt = 0; mt < 2; ++mt)
                #pragma unroll
                for (int kk = 0; kk < 2; ++kk)
                    #pragma unroll
                    for (int hl = 0; hl < 2; ++hl)
                        A0[s][mt][kk][hl] =
                            *(const u32x4*)(p + hl * 2048 + s * 1024 + mt * 512 + kk * 256);
    }

    // selected w (f32) survives to the epilogue
    float wR[2][4], wI[2][4];

    auto site = [&](int t, u32x4 (&Ac)[2][2][2][2], u32x4 (&An)[2][2][2][2]) {
        // 1. prefetch next site's A-frags (no barrier ever drains these)
        {
            int tn = t + 1; if (tn > 61) tn = 61;
            const unsigned* p = ws + (size_t)tn * 4096 + voffw;
            #pragma unroll
            for (int s = 0; s < 2; ++s)
                #pragma unroll
                for (int mt = 0; mt < 2; ++mt)
                    #pragma unroll
                    for (int kk = 0; kk < 2; ++kk)
                        #pragma unroll
                        for (int hl = 0; hl < 2; ++hl)
                            An[s][mt][kk][hl] =
                                *(const u32x4*)(p + hl * 2048 + s * 1024 + mt * 512 + kk * 256);
        }

        // 2. derive V variants: Vr = (vr,-vi) (xor hi sign), Vi = (vi,vr) (swap)
        u32x4 VrH[2], VrL[2], ViH[2], ViL[2];
        #pragma unroll
        for (int kk = 0; kk < 2; ++kk)
            #pragma unroll
            for (int q = 0; q < 4; ++q) {
                VrH[kk][q] = Bh[kk][q] ^ 0x80000000u;
                VrL[kk][q] = Bl[kk][q] ^ 0x80000000u;
                ViH[kk][q] = __builtin_amdgcn_alignbit(Bh[kk][q], Bh[kk][q], 16);
                ViL[kk][q] = __builtin_amdgcn_alignbit(Bl[kk][q], Bl[kk][q], 16);
            }

        // 3. 48 MFMAs: 8 independent 6-deep chains (spin2 x mt2 x {R,I})
        f32x4 aR[2][2], aI[2][2];
        #pragma unroll
        for (int s = 0; s < 2; ++s)
            #pragma unroll
            for (int mt = 0; mt < 2; ++mt) {
                f32x4 r = {0.f, 0.f, 0.f, 0.f};
                f32x4 im = {0.f, 0.f, 0.f, 0.f};
                #pragma unroll
                for (int kk = 0; kk < 2; ++kk) {
                    r  = MFMA16(Ac[s][mt][kk][0], VrH[kk], r);
                    r  = MFMA16(Ac[s][mt][kk][0], VrL[kk], r);
                    r  = MFMA16(Ac[s][mt][kk][1], VrH[kk], r);
                    im = MFMA16(Ac[s][mt][kk][0], ViH[kk], im);
                    im = MFMA16(Ac[s][mt][kk][0], ViL[kk], im);
                    im = MFMA16(Ac[s][mt][kk][1], ViH[kk], im);
                }
                aR[s][mt] = r; aI[s][mt] = im;
            }

        // 4. spin select (per-lane) + repack: C rows j=mt*16+4lg+r feed
        //    B-frag (kk=mt, word r) of the next site — identity wiring via beta.
        const int bp = t + 1;
        const unsigned mw  = (bp < 32) ? em0 : em1;
        const unsigned bit = (mw >> (bp & 31)) & 1u;
        #pragma unroll
        for (int mt = 0; mt < 2; ++mt)
            #pragma unroll
            for (int r = 0; r < 4; ++r) {
                const float wr = bit ? aR[1][mt][r] : aR[0][mt][r];
                const float wi = bit ? aI[1][mt][r] : aI[0][mt][r];
                wR[mt][r] = wr; wI[mt][r] = wi;
                const unsigned h = cvt_pk_bf16(wr, wi);
                Bh[mt][r] = h;
                Bl[mt][r] = cvt_pk_bf16(wr - lo_f(h), wi - hi_f(h));
            }
    };

    #pragma unroll 1
    for (int tt = 0; tt < 31; ++tt) {
        site(2 * tt,     A0, A1);
        site(2 * tt + 1, A1, A0);
    }

    // ---- right contraction: per-lane partial over its 8 j's, then
    //      xor-shuffle reduce across the 4 lg groups ----
    {
        const int sR = (int)((em1 >> 31) & 1u);
        float pr = 0.f, pi = 0.f;
        #pragma unroll
        for (int mt = 0; mt < 2; ++mt)
            #pragma unroll
            for (int r = 0; r < 4; ++r) {
                const int j = mt * 16 + 4 * lg + r;
                const float Rr = right_r[sR * 32 + j];
                const float Ri = right_i[sR * 32 + j];
                pr += wR[mt][r] * Rr - wI[mt][r] * Ri;
                pi += wR[mt][r] * Ri + wI[mt][r] * Rr;
            }
        pr += __shfl_xor(pr, 16, 64); pi += __shfl_xor(pi, 16, 64);
        pr += __shfl_xor(pr, 32, 64); pi += __shfl_xor(pi, 32, 64);
        if (lg == 0) out[eg] = make_float2(pr, pi);
    }
}

// ---------------- fallback (round-4 kernel) if ws too small ----------------
__global__ __launch_bounds__(256, 1) void mps_mfma_kernel_fb(
    const int*   __restrict__ spin,
    const float* __restrict__ left_r,  const float* __restrict__ left_i,
    const float* __restrict__ bulk_r,  const float* __restrict__ bulk_i,
    const float* __restrict__ right_r, const float* __restrict__ right_i,
    float2*      __restrict__ out)
{
    __shared__ unsigned short Bf[2][2][2][2][4][32][8];
    __shared__ float vT[2][64][33];
    __shared__ float2 red[32][8];
    __shared__ unsigned smask[32][2];

    const int tid  = threadIdx.x;
    const int l    = tid & 63;
    const int wid  = tid >> 6;
    const int mt   = wid >> 1;
    const int nt   = wid & 1;
    const int lr16 = l & 15;
    const int lg   = l >> 4;
    const int ve   = mt * 16 + lr16;
    const int jc   = nt * 16 + lr16;
    const int blk  = blockIdx.x;
    const int ccol = tid & 31;
    const int c0   = tid >> 5;

    auto convert = [&](int site, int buf) {
        const float* br = bulk_r + (size_t)site * 2048 + ccol;
        const float* bi = bulk_i + (size_t)site * 2048 + ccol;
        #pragma unroll
        for (int h = 0; h < 2; ++h) {
            const int c  = c0 + h * 8;
            const int s  = c >> 3;
            const int kk = (c >> 2) & 1;
            const int g  = c & 3;
            const int ub = kk * 16 + 2 * g;
            const float* R = br + s * 1024;
            const float* I = bi + s * 1024;
            float v0 = R[(ub + 0) * 32], v1 = I[(ub + 0) * 32];
            float v2 = R[(ub + 1) * 32], v3 = I[(ub + 1) * 32];
            float v4 = R[(ub + 8) * 32], v5 = I[(ub + 8) * 32];
            float v6 = R[(ub + 9) * 32], v7 = I[(ub + 9) * 32];
            unsigned h0 = cvt_pk_bf16(v0, v1), h1 = cvt_pk_bf16(v2, v3);
            unsigned h2 = cvt_pk_bf16(v4, v5), h3 = cvt_pk_bf16(v6, v7);
            unsigned l0 = cvt_pk_bf16(v0 - lo_f(h0), v1 - hi_f(h0));
            unsigned l1 = cvt_pk_bf16(v2 - lo_f(h1), v3 - hi_f(h1));
            unsigned l2 = cvt_pk_bf16(v4 - lo_f(h2), v5 - hi_f(h2));
            unsigned l3 = cvt_pk_bf16(v6 - lo_f(h3), v7 - hi_f(h3));
            *(u32x4*)&Bf[buf][0][s][kk][g][ccol][0] = (u32x4){h0, h1, h2, h3};
            *(u32x4*)&Bf[buf][1][s][kk][g][ccol][0] = (u32x4){l0, l1, l2, l3};
        }
    };

    if (tid < 32) {
        const int* sp = spin + ((size_t)(blk * 32 + tid)) * 64;
        unsigned a0 = 0, a1 = 0;
        #pragma unroll
        for (int k = 0; k < 32; ++k) a0 |= (unsigned)(sp[k] & 1) << k;
        #pragma unroll
        for (int k = 0; k < 32; ++k) a1 |= (unsigned)(sp[32 + k] & 1) << k;
        smask[tid][0] = a0; smask[tid][1] = a1;
    }
    {
        const int e = tid & 31, jg = tid >> 5;
        const int s0 = spin[((size_t)(blk * 32 + e)) * 64] & 1;
        #pragma unroll
        for (int d = 0; d < 4; ++d) {
            const int j = jg * 4 + d;
            vT[0][2 * j    ][e] = left_r[s0 * 32 + j];
            vT[0][2 * j + 1][e] = left_i[s0 * 32 + j];
        }
    }
    convert(0, 0);
    __syncthreads();

    unsigned em0[4], em1[4];
    #pragma unroll
    for (int r = 0; r < 4; ++r) {
        const int ee = mt * 16 + lg * 4 + r;
        em0[r] = smask[ee][0];
        em1[r] = smask[ee][1];
    }

    #pragma unroll 2
    for (int t = 0; t < 62; ++t) {
        const int b = t & 1;
        float f[16];
        #pragma unroll
        for (int kk = 0; kk < 2; ++kk)
            #pragma unroll
            for (int q = 0; q < 2; ++q)
                #pragma unroll
                for (int r = 0; r < 4; ++r)
                    f[kk * 8 + q * 4 + r] = vT[b][kk * 32 + q * 16 + 4 * lg + r][ve];

        u32x4 Vh[2], Vl[2];
        #pragma unroll
        for (int kk = 0; kk < 2; ++kk)
            #pragma unroll
            for (int q = 0; q < 2; ++q) {
                const float a = f[kk*8+q*4+0], c2 = f[kk*8+q*4+1];
                const float d2 = f[kk*8+q*4+2], e2 = f[kk*8+q*4+3];
                const unsigned h0 = cvt_pk_bf16(a, c2);
                const unsigned h1 = cvt_pk_bf16(d2, e2);
                Vh[kk][q*2+0] = h0;
                Vh[kk][q*2+1] = h1;
                Vl[kk][q*2+0] = cvt_pk_bf16(a - lo_f(h0), c2 - hi_f(h0));
                Vl[kk][q*2+1] = cvt_pk_bf16(d2 - lo_f(h1), e2 - hi_f(h1));
            }

        u32x4 Bh[2][2], Bl[2][2];
        #pragma unroll
        for (int s = 0; s < 2; ++s)
            #pragma unroll
            for (int kk = 0; kk < 2; ++kk) {
                Bh[s][kk] = *(const u32x4*)&Bf[b][0][s][kk][lg][jc][0];
                Bl[s][kk] = *(const u32x4*)&Bf[b][1][s][kk][lg][jc][0];
            }

        if (t < 61) convert(t + 1, b ^ 1);

        f32x4 ar[2] = {{0,0,0,0},{0,0,0,0}};
        f32x4 ai[2] = {{0,0,0,0},{0,0,0,0}};
        #pragma unroll
        for (int kk = 0; kk < 2; ++kk) {
            u32x4 vh, vl;
            #pragma unroll
            for (int q = 0; q < 4; ++q) {
                vh[q] = Vh[kk][q] ^ 0x80000000u;
                vl[q] = Vl[kk][q] ^ 0x80000000u;
            }
            #pragma unroll
            for (int s = 0; s < 2; ++s) {
                ar[s] = MFMA16(vh, Bh[s][kk], ar[s]);
                ar[s] = MFMA16(vh, Bl[s][kk], ar[s]);
                ar[s] = MFMA16(vl, Bh[s][kk], ar[s]);
            }
        }
        #pragma unroll
        for (int kk = 0; kk < 2; ++kk) {
            u32x4 vh, vl;
            #pragma unroll
            for (int q = 0; q < 4; ++q) {
                vh[q] = __builtin_amdgcn_alignbit(Vh[kk][q], Vh[kk][q], 16);
                vl[q] = __builtin_amdgcn_alignbit(Vl[kk][q], Vl[kk][q], 16);
            }
            #pragma unroll
            for (int s = 0; s < 2; ++s) {
                ai[s] = MFMA16(vh, Bh[s][kk], ai[s]);
                ai[s] = MFMA16(vh, Bl[s][kk], ai[s]);
                ai[s] = MFMA16(vl, Bh[s][kk], ai[s]);
            }
        }

        const int bp = t + 1;
        #pragma unroll
        for (int r = 0; r < 4; ++r) {
            const unsigned mw = (bp < 32) ? em0[r] : em1[r];
            const bool sb = (mw >> (bp & 31)) & 1u;
            const int ee = mt * 16 + lg * 4 + r;
            vT[b ^ 1][2 * jc    ][ee] = sb ? ar[1][r] : ar[0][r];
            vT[b ^ 1][2 * jc + 1][ee] = sb ? ai[1][r] : ai[0][r];
        }
        __syncthreads();
    }

    {
        const int e = tid & 31, jg = tid >> 5;
        const unsigned sR = (smask[e][1] >> 31) & 1u;
        const float* Rr = right_r + sR * 32;
        const float* Ri = right_i + sR * 32;
        float pr = 0.f, pi = 0.f;
        #pragma unroll
        for (int d = 0; d < 4; ++d) {
            const int j = jg * 4 + d;
            const float vr = vT[0][2 * j][e], vi = vT[0][2 * j + 1][e];
            pr += vr * Rr[j] - vi * Ri[j];
            pi += vr * Ri[j] + vi * Rr[j];
        }
        red[e][jg] = make_float2(pr, pi);
    }
    __syncthreads();
    if (tid < 32) {
        float2 a = red[tid][0];
        #pragma unroll
        for (int k = 1; k < 8; ++k) { a.x += red[tid][k].x; a.y += red[tid][k].y; }
        out[blk * 32 + tid] = a;
    }
}

extern "C" void kernel_launch(void* const* d_in, const int* in_sizes, int n_in,
                              void* d_out, int out_size, void* d_ws, size_t ws_size,
                              hipStream_t stream)
{
    const int*   spin = (const int*)  d_in[0];
    const float* lr   = (const float*)d_in[1];
    const float* li   = (const float*)d_in[2];
    const float* br   = (const float*)d_in[3];
    const float* bi   = (const float*)d_in[4];
    const float* rr   = (const float*)d_in[5];
    const float* ri   = (const float*)d_in[6];
    float2* out = (float2*)d_out;

    const size_t WS_NEEDED = (size_t)62 * 16384;   // 992 KB
    if (ws_size >= WS_NEEDED) {
        unsigned* ws = (unsigned*)d_ws;
        mps_preconvert<<<dim3(62), dim3(256), 0, stream>>>(br, bi, ws);
        mps_chain_kernel<<<dim3(256), dim3(128), 0, stream>>>(spin, lr, li, rr, ri, ws, out);
    } else {
        mps_mfma_kernel_fb<<<dim3(256), dim3(256), 0, stream>>>(spin, lr, li, br, bi, rr, ri, out);
    }
}

// Round 10
// 50.145 us; speedup vs baseline: 1.7885x; 1.7885x over previous
//
#include <hip/hip_runtime.h>
#include <stdint.h>

// MPS amplitude via MFMA, round 10.
// Pre-kernel converts bulk (62 sites x 2 spins) to bf16 hi/lo B-fragments in
// d_ws (16KB/site, 992KB, L2-resident). Main kernel: 512 blocks x 256 threads
// (16 elements/block, 4 waves = nt x sw, M=16) -> 2 independent blocks/CU.
// vs R8 (failed, absmax 2528): plain __syncthreads() (no inline-asm barrier)
// and NO forced min-waves launch bound (no 128-VGPR spill pressure) — the
// two codegen-risk deltas vs proven R7. Geometry/indexing identical to R8
// (re-verified against A/B/C MFMA layouts and qperm word mapping).
// s_setprio(1) wraps the MFMA cluster (T5: 2 block groups = phase diversity).

typedef __attribute__((ext_vector_type(4))) float        f32x4;
typedef __attribute__((ext_vector_type(8))) short        s16x8;
typedef __attribute__((ext_vector_type(4))) unsigned int u32x4;

__device__ __forceinline__ unsigned cvt_pk_bf16(float lo, float hi) {
    unsigned r;
    asm("v_cvt_pk_bf16_f32 %0, %1, %2" : "=v"(r) : "v"(lo), "v"(hi));
    return r;
}
__device__ __forceinline__ float lo_f(unsigned h) { return __uint_as_float(h << 16); }
__device__ __forceinline__ float hi_f(unsigned h) { return __uint_as_float(h & 0xFFFF0000u); }
__device__ __forceinline__ s16x8 frg(u32x4 x) { return __builtin_bit_cast(s16x8, x); }
#define MFMA16(A, B, C) __builtin_amdgcn_mfma_f32_16x16x32_bf16(frg(A), frg(B), C, 0, 0, 0)

// storage permutation: complex column u -> fragment word slot (verified:
// slot 4*lg+q of lane lg holds u in {2lg, 2lg+1, 8+2lg, 9+2lg} (+16 per kk))
__device__ __forceinline__ int qperm(int u) {
    return (u >> 4) * 16 + ((u >> 1) & 3) * 4 + ((u >> 3) & 1) * 2 + (u & 1);
}

// ws layout (u32 units), per site (stride 4096):
//   off = hl*2048 + s*1024 + kk*512 + g*128 + col*4 + q     (q = 0..3)
__global__ __launch_bounds__(256, 1) void mps_preconvert(
    const float* __restrict__ bulk_r, const float* __restrict__ bulk_i,
    unsigned* __restrict__ ws)
{
    const int site = blockIdx.x;          // 0..61
    const int tid  = threadIdx.x;
    const int ccol = tid & 31;
    const int c0   = tid >> 5;
    const float* br = bulk_r + (size_t)site * 2048 + ccol;
    const float* bi = bulk_i + (size_t)site * 2048 + ccol;
    unsigned* wsu = ws + (size_t)site * 4096;
    #pragma unroll
    for (int h = 0; h < 2; ++h) {
        const int c  = c0 + h * 8;
        const int s  = c >> 3;
        const int kk = (c >> 2) & 1;
        const int g  = c & 3;
        const int ub = kk * 16 + 2 * g;
        const float* R = br + s * 1024;
        const float* I = bi + s * 1024;
        float v0 = R[(ub + 0) * 32], v1 = I[(ub + 0) * 32];
        float v2 = R[(ub + 1) * 32], v3 = I[(ub + 1) * 32];
        float v4 = R[(ub + 8) * 32], v5 = I[(ub + 8) * 32];
        float v6 = R[(ub + 9) * 32], v7 = I[(ub + 9) * 32];
        unsigned h0 = cvt_pk_bf16(v0, v1), h1 = cvt_pk_bf16(v2, v3);
        unsigned h2 = cvt_pk_bf16(v4, v5), h3 = cvt_pk_bf16(v6, v7);
        unsigned l0 = cvt_pk_bf16(v0 - lo_f(h0), v1 - hi_f(h0));
        unsigned l1 = cvt_pk_bf16(v2 - lo_f(h1), v3 - hi_f(h1));
        unsigned l2 = cvt_pk_bf16(v4 - lo_f(h2), v5 - hi_f(h2));
        unsigned l3 = cvt_pk_bf16(v6 - lo_f(h3), v7 - hi_f(h3));
        const unsigned base = (unsigned)(s * 1024 + kk * 512 + g * 128 + ccol * 4);
        *(u32x4*)(wsu + base)        = (u32x4){h0, h1, h2, h3};
        *(u32x4*)(wsu + 2048 + base) = (u32x4){l0, l1, l2, l3};
    }
}

__global__ __launch_bounds__(256) void mps_mfma5_kernel(
    const int*   __restrict__ spin,
    const float* __restrict__ left_r,  const float* __restrict__ left_i,
    const float* __restrict__ right_r, const float* __restrict__ right_i,
    const unsigned* __restrict__ ws,
    float2*      __restrict__ out)
{
    __shared__ unsigned Vst[2][16 * 68];   // [buf][e*68 + {slot hi, 32+slot lo}]
    __shared__ float2 red[16][8];
    __shared__ unsigned smask[16][2];

    const int tid  = threadIdx.x;
    const int l    = tid & 63;
    const int wid  = tid >> 6;            // 0..3
    const int nt   = wid >> 1;            // column half
    const int sw   = wid & 1;             // spin this wave computes
    const int lr16 = l & 15;
    const int lg   = l >> 4;
    const int jc   = nt * 16 + lr16;      // C column (j)
    const int qjc  = qperm(jc);
    const int e0   = blockIdx.x * 16;

    // ---- spin masks (16 elements) ----
    if (tid < 16) {
        const int* sp = spin + (size_t)(e0 + tid) * 64;
        unsigned a0 = 0, a1 = 0;
        #pragma unroll
        for (int k = 0; k < 32; ++k) a0 |= (unsigned)(sp[k] & 1) << k;
        #pragma unroll
        for (int k = 0; k < 32; ++k) a1 |= (unsigned)(sp[32 + k] & 1) << k;
        smask[tid][0] = a0; smask[tid][1] = a1;
    }

    // ---- init v = left[s0] as packed hi/lo (q-permuted) ----
    {
        const int e  = tid & 15;
        const int j0 = (tid >> 4) * 2;    // 0..30
        const int s0 = spin[(size_t)(e0 + e) * 64] & 1;
        #pragma unroll
        for (int d = 0; d < 2; ++d) {
            const int j  = j0 + d;
            const int qj = qperm(j);
            const float vr = left_r[s0 * 32 + j], vi = left_i[s0 * 32 + j];
            const unsigned h  = cvt_pk_bf16(vr, vi);
            const unsigned lo = cvt_pk_bf16(vr - lo_f(h), vi - hi_f(h));
            Vst[0][e * 68 + qj]      = h;
            Vst[0][e * 68 + 32 + qj] = lo;
        }
    }

    // ---- issue site-0 B-fragment loads ----
    const unsigned* pb0 = ws + sw * 1024 + lg * 128 + jc * 4;
    u32x4 Ah0 = *(const u32x4*)(pb0);
    u32x4 Ah1 = *(const u32x4*)(pb0 + 512);
    u32x4 Al0 = *(const u32x4*)(pb0 + 2048);
    u32x4 Al1 = *(const u32x4*)(pb0 + 2560);
    u32x4 Bh0, Bh1, Bl0, Bl1;

    __syncthreads();

    // per-lane spin words for its 4 C-row elements (rows lg*4+r)
    unsigned em0[4], em1[4];
    #pragma unroll
    for (int r = 0; r < 4; ++r) {
        em0[r] = smask[lg * 4 + r][0];
        em1[r] = smask[lg * 4 + r][1];
    }

    auto site = [&](int t, const unsigned* Vin, unsigned* Vout,
                    const u32x4& Ph0, const u32x4& Ph1,
                    const u32x4& Pl0, const u32x4& Pl1,
                    u32x4& Nh0, u32x4& Nh1, u32x4& Nl0, u32x4& Nl1) {
        // prefetch next site's B fragments
        {
            int tn = t + 1; if (tn > 61) tn = 61;
            const unsigned* pb = ws + (size_t)tn * 4096 + sw * 1024 + lg * 128 + jc * 4;
            Nh0 = *(const u32x4*)(pb);
            Nh1 = *(const u32x4*)(pb + 512);
            Nl0 = *(const u32x4*)(pb + 2048);
            Nl1 = *(const u32x4*)(pb + 2560);
        }

        // V fragment reads (4 x ds_read_b128): A-row = element = lr16
        const unsigned* pv = Vin + lr16 * 68 + 4 * lg;
        u32x4 Vh0 = *(const u32x4*)(pv);
        u32x4 Vh1 = *(const u32x4*)(pv + 16);
        u32x4 Vl0 = *(const u32x4*)(pv + 32);
        u32x4 Vl1 = *(const u32x4*)(pv + 48);

        // derive V_r = (vr,-vi) and V_i = (vi,vr) for hi and lo
        u32x4 r_h0, r_h1, r_l0, r_l1, i_h0, i_h1, i_l0, i_l1;
        #pragma unroll
        for (int q = 0; q < 4; ++q) {
            r_h0[q] = Vh0[q] ^ 0x80000000u;
            r_h1[q] = Vh1[q] ^ 0x80000000u;
            r_l0[q] = Vl0[q] ^ 0x80000000u;
            r_l1[q] = Vl1[q] ^ 0x80000000u;
            i_h0[q] = __builtin_amdgcn_alignbit(Vh0[q], Vh0[q], 16);
            i_h1[q] = __builtin_amdgcn_alignbit(Vh1[q], Vh1[q], 16);
            i_l0[q] = __builtin_amdgcn_alignbit(Vl0[q], Vl0[q], 16);
            i_l1[q] = __builtin_amdgcn_alignbit(Vl1[q], Vl1[q], 16);
        }

        // 12 MFMAs: two parallel kk-chains per output (dep depth 3)
        f32x4 arA = {0.f,0.f,0.f,0.f}, arB = {0.f,0.f,0.f,0.f};
        f32x4 aiA = {0.f,0.f,0.f,0.f}, aiB = {0.f,0.f,0.f,0.f};
        __builtin_amdgcn_s_setprio(1);
        arA = MFMA16(r_h0, Ph0, arA); arA = MFMA16(r_h0, Pl0, arA); arA = MFMA16(r_l0, Ph0, arA);
        arB = MFMA16(r_h1, Ph1, arB); arB = MFMA16(r_h1, Pl1, arB); arB = MFMA16(r_l1, Ph1, arB);
        aiA = MFMA16(i_h0, Ph0, aiA); aiA = MFMA16(i_h0, Pl0, aiA); aiA = MFMA16(i_l0, Ph0, aiA);
        aiB = MFMA16(i_h1, Ph1, aiB); aiB = MFMA16(i_h1, Pl1, aiB); aiB = MFMA16(i_l1, Ph1, aiB);
        __builtin_amdgcn_s_setprio(0);
        f32x4 ar = arA + arB;
        f32x4 ai = aiA + aiB;

        // winning spin-wave packs and writes v_next (q-permuted)
        const int bp = t + 1;
        #pragma unroll
        for (int r = 0; r < 4; ++r) {
            const unsigned mw = (bp < 32) ? em0[r] : em1[r];
            const int sb = (int)((mw >> (bp & 31)) & 1u);
            if (sb == sw) {
                const int ee = lg * 4 + r;
                const unsigned h  = cvt_pk_bf16(ar[r], ai[r]);
                const unsigned lo = cvt_pk_bf16(ar[r] - lo_f(h), ai[r] - hi_f(h));
                Vout[ee * 68 + qjc]      = h;
                Vout[ee * 68 + 32 + qjc] = lo;
            }
        }
        __syncthreads();
    };

    #pragma unroll 1
    for (int tt = 0; tt < 31; ++tt) {
        site(2 * tt,     Vst[0], Vst[1], Ah0, Ah1, Al0, Al1, Bh0, Bh1, Bl0, Bl1);
        site(2 * tt + 1, Vst[1], Vst[0], Bh0, Bh1, Bl0, Bl1, Ah0, Ah1, Al0, Al1);
    }

    // ---- right contraction ----
    if (tid < 128) {
        const int e = tid & 15, jg = tid >> 4;    // jg 0..7
        const unsigned sR = (smask[e][1] >> 31) & 1u;
        const float* Rr = right_r + sR * 32;
        const float* Ri = right_i + sR * 32;
        float pr = 0.f, pi = 0.f;
        #pragma unroll
        for (int d = 0; d < 4; ++d) {
            const int j  = jg * 4 + d;
            const int qj = qperm(j);
            const unsigned h  = Vst[0][e * 68 + qj];
            const unsigned lo = Vst[0][e * 68 + 32 + qj];
            const float vr = lo_f(h) + lo_f(lo);
            const float vi = hi_f(h) + hi_f(lo);
            pr += vr * Rr[j] - vi * Ri[j];
            pi += vr * Ri[j] + vi * Rr[j];
        }
        red[e][jg] = make_float2(pr, pi);
    }
    __syncthreads();
    if (tid < 16) {
        float2 a = red[tid][0];
        #pragma unroll
        for (int k = 1; k < 8; ++k) { a.x += red[tid][k].x; a.y += red[tid][k].y; }
        out[e0 + tid] = a;
    }
}

// ---------------- fallback (round-4 kernel) if ws too small ----------------
__global__ __launch_bounds__(256, 1) void mps_mfma_kernel_fb(
    const int*   __restrict__ spin,
    const float* __restrict__ left_r,  const float* __restrict__ left_i,
    const float* __restrict__ bulk_r,  const float* __restrict__ bulk_i,
    const float* __restrict__ right_r, const float* __restrict__ right_i,
    float2*      __restrict__ out)
{
    __shared__ unsigned short Bf[2][2][2][2][4][32][8];
    __shared__ float vT[2][64][33];
    __shared__ float2 red[32][8];
    __shared__ unsigned smask[32][2];

    const int tid  = threadIdx.x;
    const int l    = tid & 63;
    const int wid  = tid >> 6;
    const int mt   = wid >> 1;
    const int nt   = wid & 1;
    const int lr16 = l & 15;
    const int lg   = l >> 4;
    const int ve   = mt * 16 + lr16;
    const int jc   = nt * 16 + lr16;
    const int blk  = blockIdx.x;
    const int ccol = tid & 31;
    const int c0   = tid >> 5;

    auto convert = [&](int site, int buf) {
        const float* br = bulk_r + (size_t)site * 2048 + ccol;
        const float* bi = bulk_i + (size_t)site * 2048 + ccol;
        #pragma unroll
        for (int h = 0; h < 2; ++h) {
            const int c  = c0 + h * 8;
            const int s  = c >> 3;
            const int kk = (c >> 2) & 1;
            const int g  = c & 3;
            const int ub = kk * 16 + 2 * g;
            const float* R = br + s * 1024;
            const float* I = bi + s * 1024;
            float v0 = R[(ub + 0) * 32], v1 = I[(ub + 0) * 32];
            float v2 = R[(ub + 1) * 32], v3 = I[(ub + 1) * 32];
            float v4 = R[(ub + 8) * 32], v5 = I[(ub + 8) * 32];
            float v6 = R[(ub + 9) * 32], v7 = I[(ub + 9) * 32];
            unsigned h0 = cvt_pk_bf16(v0, v1), h1 = cvt_pk_bf16(v2, v3);
            unsigned h2 = cvt_pk_bf16(v4, v5), h3 = cvt_pk_bf16(v6, v7);
            unsigned l0 = cvt_pk_bf16(v0 - lo_f(h0), v1 - hi_f(h0));
            unsigned l1 = cvt_pk_bf16(v2 - lo_f(h1), v3 - hi_f(h1));
            unsigned l2 = cvt_pk_bf16(v4 - lo_f(h2), v5 - hi_f(h2));
            unsigned l3 = cvt_pk_bf16(v6 - lo_f(h3), v7 - hi_f(h3));
            *(u32x4*)&Bf[buf][0][s][kk][g][ccol][0] = (u32x4){h0, h1, h2, h3};
            *(u32x4*)&Bf[buf][1][s][kk][g][ccol][0] = (u32x4){l0, l1, l2, l3};
        }
    };

    if (tid < 32) {
        const int* sp = spin + ((size_t)(blk * 32 + tid)) * 64;
        unsigned a0 = 0, a1 = 0;
        #pragma unroll
        for (int k = 0; k < 32; ++k) a0 |= (unsigned)(sp[k] & 1) << k;
        #pragma unroll
        for (int k = 0; k < 32; ++k) a1 |= (unsigned)(sp[32 + k] & 1) << k;
        smask[tid][0] = a0; smask[tid][1] = a1;
    }
    {
        const int e = tid & 31, jg = tid >> 5;
        const int s0 = spin[((size_t)(blk * 32 + e)) * 64] & 1;
        #pragma unroll
        for (int d = 0; d < 4; ++d) {
            const int j = jg * 4 + d;
            vT[0][2 * j    ][e] = left_r[s0 * 32 + j];
            vT[0][2 * j + 1][e] = left_i[s0 * 32 + j];
        }
    }
    convert(0, 0);
    __syncthreads();

    unsigned em0[4], em1[4];
    #pragma unroll
    for (int r = 0; r < 4; ++r) {
        const int ee = mt * 16 + lg * 4 + r;
        em0[r] = smask[ee][0];
        em1[r] = smask[ee][1];
    }

    #pragma unroll 2
    for (int t = 0; t < 62; ++t) {
        const int b = t & 1;
        float f[16];
        #pragma unroll
        for (int kk = 0; kk < 2; ++kk)
            #pragma unroll
            for (int q = 0; q < 2; ++q)
                #pragma unroll
                for (int r = 0; r < 4; ++r)
                    f[kk * 8 + q * 4 + r] = vT[b][kk * 32 + q * 16 + 4 * lg + r][ve];

        u32x4 Vh[2], Vl[2];
        #pragma unroll
        for (int kk = 0; kk < 2; ++kk)
            #pragma unroll
            for (int q = 0; q < 2; ++q) {
                const float a = f[kk*8+q*4+0], c2 = f[kk*8+q*4+1];
                const float d2 = f[kk*8+q*4+2], e2 = f[kk*8+q*4+3];
                const unsigned h0 = cvt_pk_bf16(a, c2);
                const unsigned h1 = cvt_pk_bf16(d2, e2);
                Vh[kk][q*2+0] = h0;
                Vh[kk][q*2+1] = h1;
                Vl[kk][q*2+0] = cvt_pk_bf16(a - lo_f(h0), c2 - hi_f(h0));
                Vl[kk][q*2+1] = cvt_pk_bf16(d2 - lo_f(h1), e2 - hi_f(h1));
            }

        u32x4 Bh[2][2], Bl[2][2];
        #pragma unroll
        for (int s = 0; s < 2; ++s)
            #pragma unroll
            for (int kk = 0; kk < 2; ++kk) {
                Bh[s][kk] = *(const u32x4*)&Bf[b][0][s][kk][lg][jc][0];
                Bl[s][kk] = *(const u32x4*)&Bf[b][1][s][kk][lg][jc][0];
            }

        if (t < 61) convert(t + 1, b ^ 1);

        f32x4 ar[2] = {{0,0,0,0},{0,0,0,0}};
        f32x4 ai[2] = {{0,0,0,0},{0,0,0,0}};
        #pragma unroll
        for (int kk = 0; kk < 2; ++kk) {
            u32x4 vh, vl;
            #pragma unroll
            for (int q = 0; q < 4; ++q) {
                vh[q] = Vh[kk][q] ^ 0x80000000u;
                vl[q] = Vl[kk][q] ^ 0x80000000u;
            }
            #pragma unroll
            for (int s = 0; s < 2; ++s) {
                ar[s] = MFMA16(vh, Bh[s][kk], ar[s]);
                ar[s] = MFMA16(vh, Bl[s][kk], ar[s]);
                ar[s] = MFMA16(vl, Bh[s][kk], ar[s]);
            }
        }
        #pragma unroll
        for (int kk = 0; kk < 2; ++kk) {
            u32x4 vh, vl;
            #pragma unroll
            for (int q = 0; q < 4; ++q) {
                vh[q] = __builtin_amdgcn_alignbit(Vh[kk][q], Vh[kk][q], 16);
                vl[q] = __builtin_amdgcn_alignbit(Vl[kk][q], Vl[kk][q], 16);
            }
            #pragma unroll
            for (int s = 0; s < 2; ++s) {
                ai[s] = MFMA16(vh, Bh[s][kk], ai[s]);
                ai[s] = MFMA16(vh, Bl[s][kk], ai[s]);
                ai[s] = MFMA16(vl, Bh[s][kk], ai[s]);
            }
        }

        const int bp = t + 1;
        #pragma unroll
        for (int r = 0; r < 4; ++r) {
            const unsigned mw = (bp < 32) ? em0[r] : em1[r];
            const bool sb = (mw >> (bp & 31)) & 1u;
            const int ee = mt * 16 + lg * 4 + r;
            vT[b ^ 1][2 * jc    ][ee] = sb ? ar[1][r] : ar[0][r];
            vT[b ^ 1][2 * jc + 1][ee] = sb ? ai[1][r] : ai[0][r];
        }
        __syncthreads();
    }

    {
        const int e = tid & 31, jg = tid >> 5;
        const unsigned sR = (smask[e][1] >> 31) & 1u;
        const float* Rr = right_r + sR * 32;
        const float* Ri = right_i + sR * 32;
        float pr = 0.f, pi = 0.f;
        #pragma unroll
        for (int d = 0; d < 4; ++d) {
            const int j = jg * 4 + d;
            const float vr = vT[0][2 * j][e], vi = vT[0][2 * j + 1][e];
            pr += vr * Rr[j] - vi * Ri[j];
            pi += vr * Ri[j] + vi * Rr[j];
        }
        red[e][jg] = make_float2(pr, pi);
    }
    __syncthreads();
    if (tid < 32) {
        float2 a = red[tid][0];
        #pragma unroll
        for (int k = 1; k < 8; ++k) { a.x += red[tid][k].x; a.y += red[tid][k].y; }
        out[blk * 32 + tid] = a;
    }
}

extern "C" void kernel_launch(void* const* d_in, const int* in_sizes, int n_in,
                              void* d_out, int out_size, void* d_ws, size_t ws_size,
                              hipStream_t stream)
{
    const int*   spin = (const int*)  d_in[0];
    const float* lr   = (const float*)d_in[1];
    const float* li   = (const float*)d_in[2];
    const float* br   = (const float*)d_in[3];
    const float* bi   = (const float*)d_in[4];
    const float* rr   = (const float*)d_in[5];
    const float* ri   = (const float*)d_in[6];
    float2* out = (float2*)d_out;

    const size_t WS_NEEDED = (size_t)62 * 16384;   // 992 KB
    if (ws_size >= WS_NEEDED) {
        unsigned* ws = (unsigned*)d_ws;
        mps_preconvert<<<dim3(62), dim3(256), 0, stream>>>(br, bi, ws);
        mps_mfma5_kernel<<<dim3(512), dim3(256), 0, stream>>>(spin, lr, li, rr, ri, ws, out);
    } else {
        mps_mfma_kernel_fb<<<dim3(256), dim3(256), 0, stream>>>(spin, lr, li, br, bi, rr, ri, out);
    }
}

// Round 11
// 40.563 us; speedup vs baseline: 2.2110x; 1.2362x over previous
//
#include <hip/hip_runtime.h>
#include <stdint.h>

// MPS amplitude via MFMA, round 11: SITE-PAIR PRODUCTS.
// One-time kernel builds P[pair][combo] = A_s1(2t) @ A_s2(2t+1) in fp32 and
// stores bf16 hi/lo MFMA B-fragments in d_ws (32KB/pair x 31 = 992KB, L2).
// Main kernel: 512 blocks x 256 threads (16 elements, 4 waves = nt x cg).
// 31 chain steps (vs 62): per step each wave computes BOTH s1-combos for
// s2 = cg (24 MFMAs), selects by the element's (s1,s2) spin bits, winning
// wave writes v. Same MFMA/VMEM totals as R10, but V-read/derive/pack/
// barrier paid 31x instead of 62x. v in LDS q-permuted bf16 hi/lo pairs.

typedef __attribute__((ext_vector_type(4))) float        f32x4;
typedef __attribute__((ext_vector_type(8))) short        s16x8;
typedef __attribute__((ext_vector_type(4))) unsigned int u32x4;

__device__ __forceinline__ unsigned cvt_pk_bf16(float lo, float hi) {
    unsigned r;
    asm("v_cvt_pk_bf16_f32 %0, %1, %2" : "=v"(r) : "v"(lo), "v"(hi));
    return r;
}
__device__ __forceinline__ float lo_f(unsigned h) { return __uint_as_float(h << 16); }
__device__ __forceinline__ float hi_f(unsigned h) { return __uint_as_float(h & 0xFFFF0000u); }
__device__ __forceinline__ s16x8 frg(u32x4 x) { return __builtin_bit_cast(s16x8, x); }
#define MFMA16(A, B, C) __builtin_amdgcn_mfma_f32_16x16x32_bf16(frg(A), frg(B), C, 0, 0, 0)

// storage permutation: complex column u -> fragment word slot
__device__ __forceinline__ int qperm(int u) {
    return (u >> 4) * 16 + ((u >> 1) & 3) * 4 + ((u >> 3) & 1) * 2 + (u & 1);
}

// ---------------- pair-product build (one-time, 124 blocks) ----------------
// ws (u32 words): pair stride 8192. hi word at p*8192 + c*1024 + off,
// lo word at p*8192 + 4096 + c*1024 + off,
// off = kk*512 + g*128 + col*4 + q, matrix row i = kk*16 + 2g + (q&1) + 8*(q>>1).
__global__ __launch_bounds__(256, 1) void mps_pairbuild(
    const float* __restrict__ bulk_r, const float* __restrict__ bulk_i,
    unsigned* __restrict__ ws)
{
    const int bx = blockIdx.x;
    const int p  = bx >> 2;            // pair 0..30
    const int c  = bx & 3;             // combo = s1 + 2*s2
    const int s1 = c & 1, s2 = c >> 1;
    const float* A1r = bulk_r + ((size_t)(2 * p)     * 2 + s1) * 1024;
    const float* A1i = bulk_i + ((size_t)(2 * p)     * 2 + s1) * 1024;
    const float* A2r = bulk_r + ((size_t)(2 * p + 1) * 2 + s2) * 1024;
    const float* A2i = bulk_i + ((size_t)(2 * p + 1) * 2 + s2) * 1024;

    __shared__ float s1r[1024], s1i[1024], s2r[1024], s2i[1024];
    for (int k = threadIdx.x; k < 1024; k += 256) {
        s1r[k] = A1r[k]; s1i[k] = A1i[k];
        s2r[k] = A2r[k]; s2i[k] = A2i[k];
    }
    __syncthreads();

    const int i  = threadIdx.x >> 3;        // P row 0..31
    const int j0 = (threadIdx.x & 7) * 4;   // 4 output columns
    float pr[4] = {0,0,0,0}, pi[4] = {0,0,0,0};
    #pragma unroll 4
    for (int k = 0; k < 32; ++k) {
        const float ar = s1r[i * 32 + k], ai = s1i[i * 32 + k];
        #pragma unroll
        for (int d = 0; d < 4; ++d) {
            const float br = s2r[k * 32 + j0 + d], bi = s2i[k * 32 + j0 + d];
            pr[d] += ar * br - ai * bi;
            pi[d] += ar * bi + ai * br;
        }
    }

    unsigned* wsu = ws + (size_t)p * 8192 + (size_t)c * 1024;
    const int kk = i >> 4;
    const int i4 = i & 15;
    const int qq = (i4 & 1) | (((i4 >> 3) & 1) << 1);
    const int g  = (i4 >> 1) & 3;
    #pragma unroll
    for (int d = 0; d < 4; ++d) {
        const int off = kk * 512 + g * 128 + (j0 + d) * 4 + qq;
        const unsigned h  = cvt_pk_bf16(pr[d], pi[d]);
        const unsigned lo = cvt_pk_bf16(pr[d] - lo_f(h), pi[d] - hi_f(h));
        wsu[off]        = h;
        wsu[4096 + off] = lo;
    }
}

// ---------------- main chain kernel (31 pair-steps) ----------------
__global__ __launch_bounds__(256) void mps_pair_kernel(
    const int*   __restrict__ spin,
    const float* __restrict__ left_r,  const float* __restrict__ left_i,
    const float* __restrict__ right_r, const float* __restrict__ right_i,
    const unsigned* __restrict__ ws,
    float2*      __restrict__ out)
{
    __shared__ unsigned Vst[2][16 * 68];   // [buf][e*68 + {slot hi, 32+slot lo}]
    __shared__ float2 red[16][8];
    __shared__ unsigned smask[16][2];

    const int tid  = threadIdx.x;
    const int l    = tid & 63;
    const int wid  = tid >> 6;            // 0..3
    const int nt   = wid >> 1;            // column half
    const int cg   = wid & 1;             // s2 value this wave owns
    const int lr16 = l & 15;
    const int lg   = l >> 4;
    const int jc   = nt * 16 + lr16;      // C column (j)
    const int qjc  = qperm(jc);
    const int e0   = blockIdx.x * 16;

    // ---- spin masks (16 elements) ----
    if (tid < 16) {
        const int* sp = spin + (size_t)(e0 + tid) * 64;
        unsigned a0 = 0, a1 = 0;
        #pragma unroll
        for (int k = 0; k < 32; ++k) a0 |= (unsigned)(sp[k] & 1) << k;
        #pragma unroll
        for (int k = 0; k < 32; ++k) a1 |= (unsigned)(sp[32 + k] & 1) << k;
        smask[tid][0] = a0; smask[tid][1] = a1;
    }

    // ---- init v = left[s0] as packed hi/lo (q-permuted) ----
    {
        const int e  = tid & 15;
        const int j0 = (tid >> 4) * 2;    // 0..30
        const int s0 = spin[(size_t)(e0 + e) * 64] & 1;
        #pragma unroll
        for (int d = 0; d < 2; ++d) {
            const int j  = j0 + d;
            const int qj = qperm(j);
            const float vr = left_r[s0 * 32 + j], vi = left_i[s0 * 32 + j];
            const unsigned h  = cvt_pk_bf16(vr, vi);
            const unsigned lo = cvt_pk_bf16(vr - lo_f(h), vi - hi_f(h));
            Vst[0][e * 68 + qj]      = h;
            Vst[0][e * 68 + 32 + qj] = lo;
        }
    }

    // ---- issue pair-0 P-fragment loads: P[s1][kk][hl] ----
    const unsigned* pbw = ws + (size_t)(2 * cg) * 1024 + lg * 128 + jc * 4;
    u32x4 PA[2][2][2], PB[2][2][2];
    #pragma unroll
    for (int s1 = 0; s1 < 2; ++s1)
        #pragma unroll
        for (int kk = 0; kk < 2; ++kk)
            #pragma unroll
            for (int hl = 0; hl < 2; ++hl)
                PA[s1][kk][hl] = *(const u32x4*)(pbw + s1 * 1024 + kk * 512 + hl * 4096);

    __syncthreads();

    // per-lane spin words for its 4 C-row elements (rows lg*4+r)
    unsigned em0[4], em1[4];
    #pragma unroll
    for (int r = 0; r < 4; ++r) {
        em0[r] = smask[lg * 4 + r][0];
        em1[r] = smask[lg * 4 + r][1];
    }

    auto step = [&](int t, const unsigned* Vin, unsigned* Vout,
                    u32x4 (&Pc)[2][2][2], u32x4 (&Pn)[2][2][2]) {
        // prefetch next pair's P fragments
        {
            int tn = t + 1; if (tn > 30) tn = 30;
            const unsigned* pb = ws + (size_t)tn * 8192 + (size_t)(2 * cg) * 1024
                               + lg * 128 + jc * 4;
            #pragma unroll
            for (int s1 = 0; s1 < 2; ++s1)
                #pragma unroll
                for (int kk = 0; kk < 2; ++kk)
                    #pragma unroll
                    for (int hl = 0; hl < 2; ++hl)
                        Pn[s1][kk][hl] = *(const u32x4*)(pb + s1 * 1024 + kk * 512 + hl * 4096);
        }

        // V fragment reads (4 x ds_read_b128)
        const unsigned* pv = Vin + lr16 * 68 + 4 * lg;
        u32x4 Vh0 = *(const u32x4*)(pv);
        u32x4 Vh1 = *(const u32x4*)(pv + 16);
        u32x4 Vl0 = *(const u32x4*)(pv + 32);
        u32x4 Vl1 = *(const u32x4*)(pv + 48);

        // derive V_r = (vr,-vi) and V_i = (vi,vr), hi and lo (once per pair)
        u32x4 r_h0, r_h1, r_l0, r_l1, i_h0, i_h1, i_l0, i_l1;
        #pragma unroll
        for (int q = 0; q < 4; ++q) {
            r_h0[q] = Vh0[q] ^ 0x80000000u;
            r_h1[q] = Vh1[q] ^ 0x80000000u;
            r_l0[q] = Vl0[q] ^ 0x80000000u;
            r_l1[q] = Vl1[q] ^ 0x80000000u;
            i_h0[q] = __builtin_amdgcn_alignbit(Vh0[q], Vh0[q], 16);
            i_h1[q] = __builtin_amdgcn_alignbit(Vh1[q], Vh1[q], 16);
            i_l0[q] = __builtin_amdgcn_alignbit(Vl0[q], Vl0[q], 16);
            i_l1[q] = __builtin_amdgcn_alignbit(Vl1[q], Vl1[q], 16);
        }

        // 24 MFMAs: both s1-combos, 3-term split x 2 kk x {R,I}
        f32x4 aR0 = {0.f,0.f,0.f,0.f}, aI0 = {0.f,0.f,0.f,0.f};
        f32x4 aR1 = {0.f,0.f,0.f,0.f}, aI1 = {0.f,0.f,0.f,0.f};
        __builtin_amdgcn_s_setprio(1);
        aR0 = MFMA16(r_h0, Pc[0][0][0], aR0); aR0 = MFMA16(r_h0, Pc[0][0][1], aR0); aR0 = MFMA16(r_l0, Pc[0][0][0], aR0);
        aR0 = MFMA16(r_h1, Pc[0][1][0], aR0); aR0 = MFMA16(r_h1, Pc[0][1][1], aR0); aR0 = MFMA16(r_l1, Pc[0][1][0], aR0);
        aI0 = MFMA16(i_h0, Pc[0][0][0], aI0); aI0 = MFMA16(i_h0, Pc[0][0][1], aI0); aI0 = MFMA16(i_l0, Pc[0][0][0], aI0);
        aI0 = MFMA16(i_h1, Pc[0][1][0], aI0); aI0 = MFMA16(i_h1, Pc[0][1][1], aI0); aI0 = MFMA16(i_l1, Pc[0][1][0], aI0);
        aR1 = MFMA16(r_h0, Pc[1][0][0], aR1); aR1 = MFMA16(r_h0, Pc[1][0][1], aR1); aR1 = MFMA16(r_l0, Pc[1][0][0], aR1);
        aR1 = MFMA16(r_h1, Pc[1][1][0], aR1); aR1 = MFMA16(r_h1, Pc[1][1][1], aR1); aR1 = MFMA16(r_l1, Pc[1][1][0], aR1);
        aI1 = MFMA16(i_h0, Pc[1][0][0], aI1); aI1 = MFMA16(i_h0, Pc[1][0][1], aI1); aI1 = MFMA16(i_l0, Pc[1][0][0], aI1);
        aI1 = MFMA16(i_h1, Pc[1][1][0], aI1); aI1 = MFMA16(i_h1, Pc[1][1][1], aI1); aI1 = MFMA16(i_l1, Pc[1][1][0], aI1);
        __builtin_amdgcn_s_setprio(0);

        // spin select: s1 picks combo (cndmask), s2 picks writing wave
        const int bp1 = 2 * t + 1, bp2 = 2 * t + 2;
        #pragma unroll
        for (int r = 0; r < 4; ++r) {
            const unsigned w1 = (bp1 < 32) ? em0[r] : em1[r];
            const unsigned w2 = (bp2 < 32) ? em0[r] : em1[r];
            const int s1b = (int)((w1 >> (bp1 & 31)) & 1u);
            const int s2b = (int)((w2 >> (bp2 & 31)) & 1u);
            const float wr = s1b ? aR1[r] : aR0[r];
            const float wi = s1b ? aI1[r] : aI0[r];
            if (s2b == cg) {
                const int ee = lg * 4 + r;
                const unsigned h  = cvt_pk_bf16(wr, wi);
                const unsigned lo = cvt_pk_bf16(wr - lo_f(h), wi - hi_f(h));
                Vout[ee * 68 + qjc]      = h;
                Vout[ee * 68 + 32 + qjc] = lo;
            }
        }
        __syncthreads();
    };

    #pragma unroll 1
    for (int tt = 0; tt < 15; ++tt) {
        step(2 * tt,     Vst[0], Vst[1], PA, PB);
        step(2 * tt + 1, Vst[1], Vst[0], PB, PA);
    }
    step(30, Vst[0], Vst[1], PA, PB);     // final (odd) step -> Vst[1]

    // ---- right contraction (V in Vst[1]) ----
    if (tid < 128) {
        const int e = tid & 15, jg = tid >> 4;    // jg 0..7
        const unsigned sR = (smask[e][1] >> 31) & 1u;
        const float* Rr = right_r + sR * 32;
        const float* Ri = right_i + sR * 32;
        float pr = 0.f, pi = 0.f;
        #pragma unroll
        for (int d = 0; d < 4; ++d) {
            const int j  = jg * 4 + d;
            const int qj = qperm(j);
            const unsigned h  = Vst[1][e * 68 + qj];
            const unsigned lo = Vst[1][e * 68 + 32 + qj];
            const float vr = lo_f(h) + lo_f(lo);
            const float vi = hi_f(h) + hi_f(lo);
            pr += vr * Rr[j] - vi * Ri[j];
            pi += vr * Ri[j] + vi * Rr[j];
        }
        red[e][jg] = make_float2(pr, pi);
    }
    __syncthreads();
    if (tid < 16) {
        float2 a = red[tid][0];
        #pragma unroll
        for (int k = 1; k < 8; ++k) { a.x += red[tid][k].x; a.y += red[tid][k].y; }
        out[e0 + tid] = a;
    }
}

// ---------------- fallback (round-4 kernel) if ws too small ----------------
__global__ __launch_bounds__(256, 1) void mps_mfma_kernel_fb(
    const int*   __restrict__ spin,
    const float* __restrict__ left_r,  const float* __restrict__ left_i,
    const float* __restrict__ bulk_r,  const float* __restrict__ bulk_i,
    const float* __restrict__ right_r, const float* __restrict__ right_i,
    float2*      __restrict__ out)
{
    __shared__ unsigned short Bf[2][2][2][2][4][32][8];
    __shared__ float vT[2][64][33];
    __shared__ float2 red[32][8];
    __shared__ unsigned smask[32][2];

    const int tid  = threadIdx.x;
    const int l    = tid & 63;
    const int wid  = tid >> 6;
    const int mt   = wid >> 1;
    const int nt   = wid & 1;
    const int lr16 = l & 15;
    const int lg   = l >> 4;
    const int ve   = mt * 16 + lr16;
    const int jc   = nt * 16 + lr16;
    const int blk  = blockIdx.x;
    const int ccol = tid & 31;
    const int c0   = tid >> 5;

    typedef __attribute__((ext_vector_type(4))) unsigned int u4;
    auto convert = [&](int site, int buf) {
        const float* br = bulk_r + (size_t)site * 2048 + ccol;
        const float* bi = bulk_i + (size_t)site * 2048 + ccol;
        #pragma unroll
        for (int h = 0; h < 2; ++h) {
            const int c  = c0 + h * 8;
            const int s  = c >> 3;
            const int kk = (c >> 2) & 1;
            const int g  = c & 3;
            const int ub = kk * 16 + 2 * g;
            const float* R = br + s * 1024;
            const float* I = bi + s * 1024;
            float v0 = R[(ub + 0) * 32], v1 = I[(ub + 0) * 32];
            float v2 = R[(ub + 1) * 32], v3 = I[(ub + 1) * 32];
            float v4 = R[(ub + 8) * 32], v5 = I[(ub + 8) * 32];
            float v6 = R[(ub + 9) * 32], v7 = I[(ub + 9) * 32];
            unsigned h0 = cvt_pk_bf16(v0, v1), h1 = cvt_pk_bf16(v2, v3);
            unsigned h2 = cvt_pk_bf16(v4, v5), h3 = cvt_pk_bf16(v6, v7);
            unsigned l0 = cvt_pk_bf16(v0 - lo_f(h0), v1 - hi_f(h0));
            unsigned l1 = cvt_pk_bf16(v2 - lo_f(h1), v3 - hi_f(h1));
            unsigned l2 = cvt_pk_bf16(v4 - lo_f(h2), v5 - hi_f(h2));
            unsigned l3 = cvt_pk_bf16(v6 - lo_f(h3), v7 - hi_f(h3));
            *(u4*)&Bf[buf][0][s][kk][g][ccol][0] = (u4){h0, h1, h2, h3};
            *(u4*)&Bf[buf][1][s][kk][g][ccol][0] = (u4){l0, l1, l2, l3};
        }
    };

    if (tid < 32) {
        const int* sp = spin + ((size_t)(blk * 32 + tid)) * 64;
        unsigned a0 = 0, a1 = 0;
        #pragma unroll
        for (int k = 0; k < 32; ++k) a0 |= (unsigned)(sp[k] & 1) << k;
        #pragma unroll
        for (int k = 0; k < 32; ++k) a1 |= (unsigned)(sp[32 + k] & 1) << k;
        smask[tid][0] = a0; smask[tid][1] = a1;
    }
    {
        const int e = tid & 31, jg = tid >> 5;
        const int s0 = spin[((size_t)(blk * 32 + e)) * 64] & 1;
        #pragma unroll
        for (int d = 0; d < 4; ++d) {
            const int j = jg * 4 + d;
            vT[0][2 * j    ][e] = left_r[s0 * 32 + j];
            vT[0][2 * j + 1][e] = left_i[s0 * 32 + j];
        }
    }
    convert(0, 0);
    __syncthreads();

    unsigned em0[4], em1[4];
    #pragma unroll
    for (int r = 0; r < 4; ++r) {
        const int ee = mt * 16 + lg * 4 + r;
        em0[r] = smask[ee][0];
        em1[r] = smask[ee][1];
    }

    #pragma unroll 2
    for (int t = 0; t < 62; ++t) {
        const int b = t & 1;
        float f[16];
        #pragma unroll
        for (int kk = 0; kk < 2; ++kk)
            #pragma unroll
            for (int q = 0; q < 2; ++q)
                #pragma unroll
                for (int r = 0; r < 4; ++r)
                    f[kk * 8 + q * 4 + r] = vT[b][kk * 32 + q * 16 + 4 * lg + r][ve];

        u32x4 Vh[2], Vl[2];
        #pragma unroll
        for (int kk = 0; kk < 2; ++kk)
            #pragma unroll
            for (int q = 0; q < 2; ++q) {
                const float a = f[kk*8+q*4+0], c2 = f[kk*8+q*4+1];
                const float d2 = f[kk*8+q*4+2], e2 = f[kk*8+q*4+3];
                const unsigned h0 = cvt_pk_bf16(a, c2);
                const unsigned h1 = cvt_pk_bf16(d2, e2);
                Vh[kk][q*2+0] = h0;
                Vh[kk][q*2+1] = h1;
                Vl[kk][q*2+0] = cvt_pk_bf16(a - lo_f(h0), c2 - hi_f(h0));
                Vl[kk][q*2+1] = cvt_pk_bf16(d2 - lo_f(h1), e2 - hi_f(h1));
            }

        u32x4 Bh[2][2], Bl[2][2];
        #pragma unroll
        for (int s = 0; s < 2; ++s)
            #pragma unroll
            for (int kk = 0; kk < 2; ++kk) {
                Bh[s][kk] = *(const u32x4*)&Bf[b][0][s][kk][lg][jc][0];
                Bl[s][kk] = *(const u32x4*)&Bf[b][1][s][kk][lg][jc][0];
            }

        if (t < 61) convert(t + 1, b ^ 1);

        f32x4 ar[2] = {{0,0,0,0},{0,0,0,0}};
        f32x4 ai[2] = {{0,0,0,0},{0,0,0,0}};
        #pragma unroll
        for (int kk = 0; kk < 2; ++kk) {
            u32x4 vh, vl;
            #pragma unroll
            for (int q = 0; q < 4; ++q) {
                vh[q] = Vh[kk][q] ^ 0x80000000u;
                vl[q] = Vl[kk][q] ^ 0x80000000u;
            }
            #pragma unroll
            for (int s = 0; s < 2; ++s) {
                ar[s] = MFMA16(vh, Bh[s][kk], ar[s]);
                ar[s] = MFMA16(vh, Bl[s][kk], ar[s]);
                ar[s] = MFMA16(vl, Bh[s][kk], ar[s]);
            }
        }
        #pragma unroll
        for (int kk = 0; kk < 2; ++kk) {
            u32x4 vh, vl;
            #pragma unroll
            for (int q = 0; q < 4; ++q) {
                vh[q] = __builtin_amdgcn_alignbit(Vh[kk][q], Vh[kk][q], 16);
                vl[q] = __builtin_amdgcn_alignbit(Vl[kk][q], Vl[kk][q], 16);
            }
            #pragma unroll
            for (int s = 0; s < 2; ++s) {
                ai[s] = MFMA16(vh, Bh[s][kk], ai[s]);
                ai[s] = MFMA16(vh, Bl[s][kk], ai[s]);
                ai[s] = MFMA16(vl, Bh[s][kk], ai[s]);
            }
        }

        const int bp = t + 1;
        #pragma unroll
        for (int r = 0; r < 4; ++r) {
            const unsigned mw = (bp < 32) ? em0[r] : em1[r];
            const bool sb = (mw >> (bp & 31)) & 1u;
            const int ee = mt * 16 + lg * 4 + r;
            vT[b ^ 1][2 * jc    ][ee] = sb ? ar[1][r] : ar[0][r];
            vT[b ^ 1][2 * jc + 1][ee] = sb ? ai[1][r] : ai[0][r];
        }
        __syncthreads();
    }

    {
        const int e = tid & 31, jg = tid >> 5;
        const unsigned sR = (smask[e][1] >> 31) & 1u;
        const float* Rr = right_r + sR * 32;
        const float* Ri = right_i + sR * 32;
        float pr = 0.f, pi = 0.f;
        #pragma unroll
        for (int d = 0; d < 4; ++d) {
            const int j = jg * 4 + d;
            const float vr = vT[0][2 * j][e], vi = vT[0][2 * j + 1][e];
            pr += vr * Rr[j] - vi * Ri[j];
            pi += vr * Ri[j] + vi * Rr[j];
        }
        red[e][jg] = make_float2(pr, pi);
    }
    __syncthreads();
    if (tid < 32) {
        float2 a = red[tid][0];
        #pragma unroll
        for (int k = 1; k < 8; ++k) { a.x += red[tid][k].x; a.y += red[tid][k].y; }
        out[blk * 32 + tid] = a;
    }
}

extern "C" void kernel_launch(void* const* d_in, const int* in_sizes, int n_in,
                              void* d_out, int out_size, void* d_ws, size_t ws_size,
                              hipStream_t stream)
{
    const int*   spin = (const int*)  d_in[0];
    const float* lr   = (const float*)d_in[1];
    const float* li   = (const float*)d_in[2];
    const float* br   = (const float*)d_in[3];
    const float* bi   = (const float*)d_in[4];
    const float* rr   = (const float*)d_in[5];
    const float* ri   = (const float*)d_in[6];
    float2* out = (float2*)d_out;

    const size_t WS_NEEDED = (size_t)31 * 32768;   // 992 KB (proven available)
    if (ws_size >= WS_NEEDED) {
        unsigned* ws = (unsigned*)d_ws;
        mps_pairbuild<<<dim3(124), dim3(256), 0, stream>>>(br, bi, ws);
        mps_pair_kernel<<<dim3(512), dim3(256), 0, stream>>>(spin, lr, li, rr, ri, ws, out);
    } else {
        mps_mfma_kernel_fb<<<dim3(256), dim3(256), 0, stream>>>(spin, lr, li, br, bi, rr, ri, out);
    }
}

// Round 12
// 33.520 us; speedup vs baseline: 2.6755x; 1.2101x over previous
//
#include <hip/hip_runtime.h>
#include <stdint.h>

// MPS amplitude via MFMA, round 12: fp16 single-term P + exact 2^k rescale.
// pairbuild: P[pair][combo] = A_s1(2t) @ A_s2(2t+1) in fp32, scaled by
// 2^-(pair&1) (exact), stored as SINGLE fp16 (RTNE) MFMA B-fragments in d_ws
// (16KB/pair x 31 = 496KB, L2). Epilogue multiplies amp by 2^15 (exact).
// Main: 512 blocks x 256 thr (16 elems, 4 waves = nt x cg), 31 steps.
// Per step/wave: 4 P-loads (64B/lane, HALF of R11), 16 MFMAs
// (V 2-term fp16 hi/lo x 2 kk x {R,I} x 2 s1-combos), spin select, repack.
// v in LDS q-permuted fp16 (vr,vi) hi/lo pairs. Geometry identical to R11.

typedef __attribute__((ext_vector_type(4))) float        f32x4;
typedef __attribute__((ext_vector_type(8))) _Float16     f16x8;
typedef __attribute__((ext_vector_type(4))) unsigned int u32x4;

__device__ __forceinline__ float f16lo(unsigned u) {
    return (float)__builtin_bit_cast(_Float16, (unsigned short)(u & 0xFFFFu));
}
__device__ __forceinline__ float f16hi(unsigned u) {
    return (float)__builtin_bit_cast(_Float16, (unsigned short)(u >> 16));
}
__device__ __forceinline__ unsigned pk_rtz(float a, float b) {
    return __builtin_bit_cast(unsigned, __builtin_amdgcn_cvt_pkrtz(a, b));
}
__device__ __forceinline__ unsigned pk_rtne(float a, float b) {
    unsigned short x = __builtin_bit_cast(unsigned short, (_Float16)a);
    unsigned short y = __builtin_bit_cast(unsigned short, (_Float16)b);
    return (unsigned)x | ((unsigned)y << 16);
}
__device__ __forceinline__ f16x8 frg16(u32x4 x) { return __builtin_bit_cast(f16x8, x); }
#define MFMAH(A, B, C) __builtin_amdgcn_mfma_f32_16x16x32_f16(frg16(A), frg16(B), C, 0, 0, 0)

// storage permutation: complex column u -> fragment word slot
__device__ __forceinline__ int qperm(int u) {
    return (u >> 4) * 16 + ((u >> 1) & 3) * 4 + ((u >> 3) & 1) * 2 + (u & 1);
}

// ---------------- pair-product build (one-time, 124 blocks) ----------------
// ws (u32 words): pair stride 4096 (16KB). word at p*4096 + c*1024 + off,
// off = kk*512 + g*128 + col*4 + q, matrix row i = kk*16 + 2g + (q&1) + 8*(q>>1).
// P scaled by 2^-(p&1) before fp16 RTNE quantization.
__global__ __launch_bounds__(256, 1) void mps_pairbuild(
    const float* __restrict__ bulk_r, const float* __restrict__ bulk_i,
    unsigned* __restrict__ ws)
{
    const int bx = blockIdx.x;
    const int p  = bx >> 2;            // pair 0..30
    const int c  = bx & 3;             // combo = s1 + 2*s2
    const int s1 = c & 1, s2 = c >> 1;
    const float* A1r = bulk_r + ((size_t)(2 * p)     * 2 + s1) * 1024;
    const float* A1i = bulk_i + ((size_t)(2 * p)     * 2 + s1) * 1024;
    const float* A2r = bulk_r + ((size_t)(2 * p + 1) * 2 + s2) * 1024;
    const float* A2i = bulk_i + ((size_t)(2 * p + 1) * 2 + s2) * 1024;

    __shared__ float s1r[1024], s1i[1024], s2r[1024], s2i[1024];
    for (int k = threadIdx.x; k < 1024; k += 256) {
        s1r[k] = A1r[k]; s1i[k] = A1i[k];
        s2r[k] = A2r[k]; s2i[k] = A2i[k];
    }
    __syncthreads();

    const int i  = threadIdx.x >> 3;        // P row 0..31
    const int j0 = (threadIdx.x & 7) * 4;   // 4 output columns
    float pr[4] = {0,0,0,0}, pi[4] = {0,0,0,0};
    #pragma unroll 4
    for (int k = 0; k < 32; ++k) {
        const float ar = s1r[i * 32 + k], ai = s1i[i * 32 + k];
        #pragma unroll
        for (int d = 0; d < 4; ++d) {
            const float br = s2r[k * 32 + j0 + d], bi = s2i[k * 32 + j0 + d];
            pr[d] += ar * br - ai * bi;
            pi[d] += ar * bi + ai * br;
        }
    }

    unsigned* wsu = ws + (size_t)p * 4096 + (size_t)c * 1024;
    const int kk = i >> 4;
    const int i4 = i & 15;
    const int qq = (i4 & 1) | (((i4 >> 3) & 1) << 1);
    const int g  = (i4 >> 1) & 3;
    const float sc = (p & 1) ? 0.5f : 1.0f;   // exact 2^-(p&1)
    #pragma unroll
    for (int d = 0; d < 4; ++d) {
        const int off = kk * 512 + g * 128 + (j0 + d) * 4 + qq;
        wsu[off] = pk_rtne(pr[d] * sc, pi[d] * sc);
    }
}

// ---------------- main chain kernel (31 pair-steps) ----------------
__global__ __launch_bounds__(256) void mps_pair16_kernel(
    const int*   __restrict__ spin,
    const float* __restrict__ left_r,  const float* __restrict__ left_i,
    const float* __restrict__ right_r, const float* __restrict__ right_i,
    const unsigned* __restrict__ ws,
    float2*      __restrict__ out)
{
    __shared__ unsigned Vst[2][16 * 68];   // [buf][e*68 + {slot hi, 32+slot lo}]
    __shared__ float2 red[16][8];
    __shared__ unsigned smask[16][2];

    const int tid  = threadIdx.x;
    const int l    = tid & 63;
    const int wid  = tid >> 6;            // 0..3
    const int nt   = wid >> 1;            // column half
    const int cg   = wid & 1;             // s2 value this wave owns
    const int lr16 = l & 15;
    const int lg   = l >> 4;
    const int jc   = nt * 16 + lr16;      // C column (j)
    const int qjc  = qperm(jc);
    const int e0   = blockIdx.x * 16;

    // ---- spin masks (16 elements) ----
    if (tid < 16) {
        const int* sp = spin + (size_t)(e0 + tid) * 64;
        unsigned a0 = 0, a1 = 0;
        #pragma unroll
        for (int k = 0; k < 32; ++k) a0 |= (unsigned)(sp[k] & 1) << k;
        #pragma unroll
        for (int k = 0; k < 32; ++k) a1 |= (unsigned)(sp[32 + k] & 1) << k;
        smask[tid][0] = a0; smask[tid][1] = a1;
    }

    // ---- init v = left[s0] as packed fp16 hi/lo (q-permuted) ----
    {
        const int e  = tid & 15;
        const int j0 = (tid >> 4) * 2;    // 0..30
        const int s0 = spin[(size_t)(e0 + e) * 64] & 1;
        #pragma unroll
        for (int d = 0; d < 2; ++d) {
            const int j  = j0 + d;
            const int qj = qperm(j);
            const float vr = left_r[s0 * 32 + j], vi = left_i[s0 * 32 + j];
            const unsigned h  = pk_rtne(vr, vi);
            const unsigned lo = pk_rtne(vr - f16lo(h), vi - f16hi(h));
            Vst[0][e * 68 + qj]      = h;
            Vst[0][e * 68 + 32 + qj] = lo;
        }
    }

    // ---- issue pair-0 P-fragment loads: P[s1][kk] ----
    const unsigned* pbw = ws + (size_t)(2 * cg) * 1024 + lg * 128 + jc * 4;
    u32x4 PA[2][2], PB[2][2];
    #pragma unroll
    for (int s1 = 0; s1 < 2; ++s1)
        #pragma unroll
        for (int kk = 0; kk < 2; ++kk)
            PA[s1][kk] = *(const u32x4*)(pbw + s1 * 1024 + kk * 512);

    __syncthreads();

    // per-lane spin words for its 4 C-row elements (rows lg*4+r)
    unsigned em0[4], em1[4];
    #pragma unroll
    for (int r = 0; r < 4; ++r) {
        em0[r] = smask[lg * 4 + r][0];
        em1[r] = smask[lg * 4 + r][1];
    }

    auto step = [&](int t, const unsigned* Vin, unsigned* Vout,
                    u32x4 (&Pc)[2][2], u32x4 (&Pn)[2][2]) {
        // prefetch next pair's P fragments
        {
            int tn = t + 1; if (tn > 30) tn = 30;
            const unsigned* pb = ws + (size_t)tn * 4096 + (size_t)(2 * cg) * 1024
                               + lg * 128 + jc * 4;
            #pragma unroll
            for (int s1 = 0; s1 < 2; ++s1)
                #pragma unroll
                for (int kk = 0; kk < 2; ++kk)
                    Pn[s1][kk] = *(const u32x4*)(pb + s1 * 1024 + kk * 512);
        }

        // V fragment reads (4 x ds_read_b128)
        const unsigned* pv = Vin + lr16 * 68 + 4 * lg;
        u32x4 Vh0 = *(const u32x4*)(pv);
        u32x4 Vh1 = *(const u32x4*)(pv + 16);
        u32x4 Vl0 = *(const u32x4*)(pv + 32);
        u32x4 Vl1 = *(const u32x4*)(pv + 48);

        // derive V_r = (vr,-vi) and V_i = (vi,vr), hi and lo
        u32x4 r_h0, r_h1, r_l0, r_l1, i_h0, i_h1, i_l0, i_l1;
        #pragma unroll
        for (int q = 0; q < 4; ++q) {
            r_h0[q] = Vh0[q] ^ 0x80000000u;
            r_h1[q] = Vh1[q] ^ 0x80000000u;
            r_l0[q] = Vl0[q] ^ 0x80000000u;
            r_l1[q] = Vl1[q] ^ 0x80000000u;
            i_h0[q] = __builtin_amdgcn_alignbit(Vh0[q], Vh0[q], 16);
            i_h1[q] = __builtin_amdgcn_alignbit(Vh1[q], Vh1[q], 16);
            i_l0[q] = __builtin_amdgcn_alignbit(Vl0[q], Vl0[q], 16);
            i_l1[q] = __builtin_amdgcn_alignbit(Vl1[q], Vl1[q], 16);
        }

        // 16 MFMAs: both s1-combos, (Vh + Vl) x 2 kk x {R,I}
        f32x4 aR0 = {0.f,0.f,0.f,0.f}, aI0 = {0.f,0.f,0.f,0.f};
        f32x4 aR1 = {0.f,0.f,0.f,0.f}, aI1 = {0.f,0.f,0.f,0.f};
        __builtin_amdgcn_s_setprio(1);
        aR0 = MFMAH(r_h0, Pc[0][0], aR0); aR0 = MFMAH(r_l0, Pc[0][0], aR0);
        aR0 = MFMAH(r_h1, Pc[0][1], aR0); aR0 = MFMAH(r_l1, Pc[0][1], aR0);
        aI0 = MFMAH(i_h0, Pc[0][0], aI0); aI0 = MFMAH(i_l0, Pc[0][0], aI0);
        aI0 = MFMAH(i_h1, Pc[0][1], aI0); aI0 = MFMAH(i_l1, Pc[0][1], aI0);
        aR1 = MFMAH(r_h0, Pc[1][0], aR1); aR1 = MFMAH(r_l0, Pc[1][0], aR1);
        aR1 = MFMAH(r_h1, Pc[1][1], aR1); aR1 = MFMAH(r_l1, Pc[1][1], aR1);
        aI1 = MFMAH(i_h0, Pc[1][0], aI1); aI1 = MFMAH(i_l0, Pc[1][0], aI1);
        aI1 = MFMAH(i_h1, Pc[1][1], aI1); aI1 = MFMAH(i_l1, Pc[1][1], aI1);
        __builtin_amdgcn_s_setprio(0);

        // spin select: s1 picks combo (cndmask), s2 picks writing wave
        const int bp1 = 2 * t + 1, bp2 = 2 * t + 2;
        #pragma unroll
        for (int r = 0; r < 4; ++r) {
            const unsigned w1 = (bp1 < 32) ? em0[r] : em1[r];
            const unsigned w2 = (bp2 < 32) ? em0[r] : em1[r];
            const int s1b = (int)((w1 >> (bp1 & 31)) & 1u);
            const int s2b = (int)((w2 >> (bp2 & 31)) & 1u);
            const float wr = s1b ? aR1[r] : aR0[r];
            const float wi = s1b ? aI1[r] : aI0[r];
            if (s2b == cg) {
                const int ee = lg * 4 + r;
                const unsigned h  = pk_rtz(wr, wi);
                const unsigned lo = pk_rtz(wr - f16lo(h), wi - f16hi(h));
                Vout[ee * 68 + qjc]      = h;
                Vout[ee * 68 + 32 + qjc] = lo;
            }
        }
        __syncthreads();
    };

    #pragma unroll 1
    for (int tt = 0; tt < 15; ++tt) {
        step(2 * tt,     Vst[0], Vst[1], PA, PB);
        step(2 * tt + 1, Vst[1], Vst[0], PB, PA);
    }
    step(30, Vst[0], Vst[1], PA, PB);     // final (odd) step -> Vst[1]

    // ---- right contraction (V in Vst[1]); amp *= 2^15 (exact rescale) ----
    if (tid < 128) {
        const int e = tid & 15, jg = tid >> 4;    // jg 0..7
        const unsigned sR = (smask[e][1] >> 31) & 1u;
        const float* Rr = right_r + sR * 32;
        const float* Ri = right_i + sR * 32;
        float pr = 0.f, pi = 0.f;
        #pragma unroll
        for (int d = 0; d < 4; ++d) {
            const int j  = jg * 4 + d;
            const int qj = qperm(j);
            const unsigned h  = Vst[1][e * 68 + qj];
            const unsigned lo = Vst[1][e * 68 + 32 + qj];
            const float vr = f16lo(h) + f16lo(lo);
            const float vi = f16hi(h) + f16hi(lo);
            pr += vr * Rr[j] - vi * Ri[j];
            pi += vr * Ri[j] + vi * Rr[j];
        }
        red[e][jg] = make_float2(pr, pi);
    }
    __syncthreads();
    if (tid < 16) {
        float2 a = red[tid][0];
        #pragma unroll
        for (int k = 1; k < 8; ++k) { a.x += red[tid][k].x; a.y += red[tid][k].y; }
        out[e0 + tid] = make_float2(a.x * 32768.0f, a.y * 32768.0f);
    }
}

// ---------------- fallback (round-4 kernel) if ws too small ----------------
typedef __attribute__((ext_vector_type(8))) short s16x8;
__device__ __forceinline__ unsigned cvt_pk_bf16(float lo, float hi) {
    unsigned r;
    asm("v_cvt_pk_bf16_f32 %0, %1, %2" : "=v"(r) : "v"(lo), "v"(hi));
    return r;
}
__device__ __forceinline__ float lo_f(unsigned h) { return __uint_as_float(h << 16); }
__device__ __forceinline__ float hi_f(unsigned h) { return __uint_as_float(h & 0xFFFF0000u); }
__device__ __forceinline__ s16x8 frg(u32x4 x) { return __builtin_bit_cast(s16x8, x); }
#define MFMA16(A, B, C) __builtin_amdgcn_mfma_f32_16x16x32_bf16(frg(A), frg(B), C, 0, 0, 0)

__global__ __launch_bounds__(256, 1) void mps_mfma_kernel_fb(
    const int*   __restrict__ spin,
    const float* __restrict__ left_r,  const float* __restrict__ left_i,
    const float* __restrict__ bulk_r,  const float* __restrict__ bulk_i,
    const float* __restrict__ right_r, const float* __restrict__ right_i,
    float2*      __restrict__ out)
{
    __shared__ unsigned short Bf[2][2][2][2][4][32][8];
    __shared__ float vT[2][64][33];
    __shared__ float2 red[32][8];
    __shared__ unsigned smask[32][2];

    const int tid  = threadIdx.x;
    const int l    = tid & 63;
    const int wid  = tid >> 6;
    const int mt   = wid >> 1;
    const int nt   = wid & 1;
    const int lr16 = l & 15;
    const int lg   = l >> 4;
    const int ve   = mt * 16 + lr16;
    const int jc   = nt * 16 + lr16;
    const int blk  = blockIdx.x;
    const int ccol = tid & 31;
    const int c0   = tid >> 5;

    auto convert = [&](int site, int buf) {
        const float* br = bulk_r + (size_t)site * 2048 + ccol;
        const float* bi = bulk_i + (size_t)site * 2048 + ccol;
        #pragma unroll
        for (int h = 0; h < 2; ++h) {
            const int c  = c0 + h * 8;
            const int s  = c >> 3;
            const int kk = (c >> 2) & 1;
            const int g  = c & 3;
            const int ub = kk * 16 + 2 * g;
            const float* R = br + s * 1024;
            const float* I = bi + s * 1024;
            float v0 = R[(ub + 0) * 32], v1 = I[(ub + 0) * 32];
            float v2 = R[(ub + 1) * 32], v3 = I[(ub + 1) * 32];
            float v4 = R[(ub + 8) * 32], v5 = I[(ub + 8) * 32];
            float v6 = R[(ub + 9) * 32], v7 = I[(ub + 9) * 32];
            unsigned h0 = cvt_pk_bf16(v0, v1), h1 = cvt_pk_bf16(v2, v3);
            unsigned h2 = cvt_pk_bf16(v4, v5), h3 = cvt_pk_bf16(v6, v7);
            unsigned l0 = cvt_pk_bf16(v0 - lo_f(h0), v1 - hi_f(h0));
            unsigned l1 = cvt_pk_bf16(v2 - lo_f(h1), v3 - hi_f(h1));
            unsigned l2 = cvt_pk_bf16(v4 - lo_f(h2), v5 - hi_f(h2));
            unsigned l3 = cvt_pk_bf16(v6 - lo_f(h3), v7 - hi_f(h3));
            *(u32x4*)&Bf[buf][0][s][kk][g][ccol][0] = (u32x4){h0, h1, h2, h3};
            *(u32x4*)&Bf[buf][1][s][kk][g][ccol][0] = (u32x4){l0, l1, l2, l3};
        }
    };

    if (tid < 32) {
        const int* sp = spin + ((size_t)(blk * 32 + tid)) * 64;
        unsigned a0 = 0, a1 = 0;
        #pragma unroll
        for (int k = 0; k < 32; ++k) a0 |= (unsigned)(sp[k] & 1) << k;
        #pragma unroll
        for (int k = 0; k < 32; ++k) a1 |= (unsigned)(sp[32 + k] & 1) << k;
        smask[tid][0] = a0; smask[tid][1] = a1;
    }
    {
        const int e = tid & 31, jg = tid >> 5;
        const int s0 = spin[((size_t)(blk * 32 + e)) * 64] & 1;
        #pragma unroll
        for (int d = 0; d < 4; ++d) {
            const int j = jg * 4 + d;
            vT[0][2 * j    ][e] = left_r[s0 * 32 + j];
            vT[0][2 * j + 1][e] = left_i[s0 * 32 + j];
        }
    }
    convert(0, 0);
    __syncthreads();

    unsigned em0[4], em1[4];
    #pragma unroll
    for (int r = 0; r < 4; ++r) {
        const int ee = mt * 16 + lg * 4 + r;
        em0[r] = smask[ee][0];
        em1[r] = smask[ee][1];
    }

    #pragma unroll 2
    for (int t = 0; t < 62; ++t) {
        const int b = t & 1;
        float f[16];
        #pragma unroll
        for (int kk = 0; kk < 2; ++kk)
            #pragma unroll
            for (int q = 0; q < 2; ++q)
                #pragma unroll
                for (int r = 0; r < 4; ++r)
                    f[kk * 8 + q * 4 + r] = vT[b][kk * 32 + q * 16 + 4 * lg + r][ve];

        u32x4 Vh[2], Vl[2];
        #pragma unroll
        for (int kk = 0; kk < 2; ++kk)
            #pragma unroll
            for (int q = 0; q < 2; ++q) {
                const float a = f[kk*8+q*4+0], c2 = f[kk*8+q*4+1];
                const float d2 = f[kk*8+q*4+2], e2 = f[kk*8+q*4+3];
                const unsigned h0 = cvt_pk_bf16(a, c2);
                const unsigned h1 = cvt_pk_bf16(d2, e2);
                Vh[kk][q*2+0] = h0;
                Vh[kk][q*2+1] = h1;
                Vl[kk][q*2+0] = cvt_pk_bf16(a - lo_f(h0), c2 - hi_f(h0));
                Vl[kk][q*2+1] = cvt_pk_bf16(d2 - lo_f(h1), e2 - hi_f(h1));
            }

        u32x4 Bh[2][2], Bl[2][2];
        #pragma unroll
        for (int s = 0; s < 2; ++s)
            #pragma unroll
            for (int kk = 0; kk < 2; ++kk) {
                Bh[s][kk] = *(const u32x4*)&Bf[b][0][s][kk][lg][jc][0];
                Bl[s][kk] = *(const u32x4*)&Bf[b][1][s][kk][lg][jc][0];
            }

        if (t < 61) convert(t + 1, b ^ 1);

        f32x4 ar[2] = {{0,0,0,0},{0,0,0,0}};
        f32x4 ai[2] = {{0,0,0,0},{0,0,0,0}};
        #pragma unroll
        for (int kk = 0; kk < 2; ++kk) {
            u32x4 vh, vl;
            #pragma unroll
            for (int q = 0; q < 4; ++q) {
                vh[q] = Vh[kk][q] ^ 0x80000000u;
                vl[q] = Vl[kk][q] ^ 0x80000000u;
            }
            #pragma unroll
            for (int s = 0; s < 2; ++s) {
                ar[s] = MFMA16(vh, Bh[s][kk], ar[s]);
                ar[s] = MFMA16(vh, Bl[s][kk], ar[s]);
                ar[s] = MFMA16(vl, Bh[s][kk], ar[s]);
            }
        }
        #pragma unroll
        for (int kk = 0; kk < 2; ++kk) {
            u32x4 vh, vl;
            #pragma unroll
            for (int q = 0; q < 4; ++q) {
                vh[q] = __builtin_amdgcn_alignbit(Vh[kk][q], Vh[kk][q], 16);
                vl[q] = __builtin_amdgcn_alignbit(Vl[kk][q], Vl[kk][q], 16);
            }
            #pragma unroll
            for (int s = 0; s < 2; ++s) {
                ai[s] = MFMA16(vh, Bh[s][kk], ai[s]);
                ai[s] = MFMA16(vh, Bl[s][kk], ai[s]);
                ai[s] = MFMA16(vl, Bh[s][kk], ai[s]);
            }
        }

        const int bp = t + 1;
        #pragma unroll
        for (int r = 0; r < 4; ++r) {
            const unsigned mw = (bp < 32) ? em0[r] : em1[r];
            const bool sb = (mw >> (bp & 31)) & 1u;
            const int ee = mt * 16 + lg * 4 + r;
            vT[b ^ 1][2 * jc    ][ee] = sb ? ar[1][r] : ar[0][r];
            vT[b ^ 1][2 * jc + 1][ee] = sb ? ai[1][r] : ai[0][r];
        }
        __syncthreads();
    }

    {
        const int e = tid & 31, jg = tid >> 5;
        const unsigned sR = (smask[e][1] >> 31) & 1u;
        const float* Rr = right_r + sR * 32;
        const float* Ri = right_i + sR * 32;
        float pr = 0.f, pi = 0.f;
        #pragma unroll
        for (int d = 0; d < 4; ++d) {
            const int j = jg * 4 + d;
            const float vr = vT[0][2 * j][e], vi = vT[0][2 * j + 1][e];
            pr += vr * Rr[j] - vi * Ri[j];
            pi += vr * Ri[j] + vi * Rr[j];
        }
        red[e][jg] = make_float2(pr, pi);
    }
    __syncthreads();
    if (tid < 32) {
        float2 a = red[tid][0];
        #pragma unroll
        for (int k = 1; k < 8; ++k) { a.x += red[tid][k].x; a.y += red[tid][k].y; }
        out[blk * 32 + tid] = a;
    }
}

extern "C" void kernel_launch(void* const* d_in, const int* in_sizes, int n_in,
                              void* d_out, int out_size, void* d_ws, size_t ws_size,
                              hipStream_t stream)
{
    const int*   spin = (const int*)  d_in[0];
    const float* lr   = (const float*)d_in[1];
    const float* li   = (const float*)d_in[2];
    const float* br   = (const float*)d_in[3];
    const float* bi   = (const float*)d_in[4];
    const float* rr   = (const float*)d_in[5];
    const float* ri   = (const float*)d_in[6];
    float2* out = (float2*)d_out;

    const size_t WS_NEEDED = (size_t)31 * 16384;   // 496 KB
    if (ws_size >= WS_NEEDED) {
        unsigned* ws = (unsigned*)d_ws;
        mps_pairbuild<<<dim3(124), dim3(256), 0, stream>>>(br, bi, ws);
        mps_pair16_kernel<<<dim3(512), dim3(256), 0, stream>>>(spin, lr, li, rr, ri, ws, out);
    } else {
        mps_mfma_kernel_fb<<<dim3(256), dim3(256), 0, stream>>>(spin, lr, li, br, bi, rr, ri, out);
    }
}

// Round 13
// 28.579 us; speedup vs baseline: 3.1380x; 1.1729x over previous
//
#include <hip/hip_runtime.h>
#include <stdint.h>

// MPS amplitude via MFMA, round 13: fp16 1-term P AND 1-term V (RTNE).
// pairbuild: P[pair][combo] = A_s1(2t) @ A_s2(2t+1) fp32, scaled 2^-(p&1)
// (exact), stored fp16 RTNE MFMA B-frags in d_ws (16KB/pair x 31, L2).
// Epilogue multiplies amp by 2^15 (exact). Main: 512 blocks x 256 thr
// (16 elems, 4 waves = nt x cg), 31 steps. Per step/wave: 4 P-loads,
// 2 ds_read_b128 (V single-term), 16 derive VALU, 8 MFMAs, RTNE repack.
// v in LDS q-permuted fp16 (vr,vi) packed words, 36 words/elem, ping-pong.

typedef __attribute__((ext_vector_type(4))) float        f32x4;
typedef __attribute__((ext_vector_type(8))) _Float16     f16x8;
typedef __attribute__((ext_vector_type(4))) unsigned int u32x4;

__device__ __forceinline__ float f16lo(unsigned u) {
    return (float)__builtin_bit_cast(_Float16, (unsigned short)(u & 0xFFFFu));
}
__device__ __forceinline__ float f16hi(unsigned u) {
    return (float)__builtin_bit_cast(_Float16, (unsigned short)(u >> 16));
}
__device__ __forceinline__ unsigned pk_rtne(float a, float b) {
    unsigned short x = __builtin_bit_cast(unsigned short, (_Float16)a);
    unsigned short y = __builtin_bit_cast(unsigned short, (_Float16)b);
    return (unsigned)x | ((unsigned)y << 16);
}
__device__ __forceinline__ f16x8 frg16(u32x4 x) { return __builtin_bit_cast(f16x8, x); }
#define MFMAH(A, B, C) __builtin_amdgcn_mfma_f32_16x16x32_f16(frg16(A), frg16(B), C, 0, 0, 0)

// storage permutation: complex column u -> fragment word slot
__device__ __forceinline__ int qperm(int u) {
    return (u >> 4) * 16 + ((u >> 1) & 3) * 4 + ((u >> 3) & 1) * 2 + (u & 1);
}

// ---------------- pair-product build (one-time, 124 blocks) ----------------
// ws (u32 words): pair stride 4096 (16KB). word at p*4096 + c*1024 + off,
// off = kk*512 + g*128 + col*4 + q, matrix row i = kk*16 + 2g + (q&1) + 8*(q>>1).
__global__ __launch_bounds__(256, 1) void mps_pairbuild(
    const float* __restrict__ bulk_r, const float* __restrict__ bulk_i,
    unsigned* __restrict__ ws)
{
    const int bx = blockIdx.x;
    const int p  = bx >> 2;            // pair 0..30
    const int c  = bx & 3;             // combo = s1 + 2*s2
    const int s1 = c & 1, s2 = c >> 1;
    const float* A1r = bulk_r + ((size_t)(2 * p)     * 2 + s1) * 1024;
    const float* A1i = bulk_i + ((size_t)(2 * p)     * 2 + s1) * 1024;
    const float* A2r = bulk_r + ((size_t)(2 * p + 1) * 2 + s2) * 1024;
    const float* A2i = bulk_i + ((size_t)(2 * p + 1) * 2 + s2) * 1024;

    __shared__ float s1r[1024], s1i[1024], s2r[1024], s2i[1024];
    for (int k = threadIdx.x; k < 1024; k += 256) {
        s1r[k] = A1r[k]; s1i[k] = A1i[k];
        s2r[k] = A2r[k]; s2i[k] = A2i[k];
    }
    __syncthreads();

    const int i  = threadIdx.x >> 3;        // P row 0..31
    const int j0 = (threadIdx.x & 7) * 4;   // 4 output columns
    float pr[4] = {0,0,0,0}, pi[4] = {0,0,0,0};
    #pragma unroll 4
    for (int k = 0; k < 32; ++k) {
        const float ar = s1r[i * 32 + k], ai = s1i[i * 32 + k];
        #pragma unroll
        for (int d = 0; d < 4; ++d) {
            const float br = s2r[k * 32 + j0 + d], bi = s2i[k * 32 + j0 + d];
            pr[d] += ar * br - ai * bi;
            pi[d] += ar * bi + ai * br;
        }
    }

    unsigned* wsu = ws + (size_t)p * 4096 + (size_t)c * 1024;
    const int kk = i >> 4;
    const int i4 = i & 15;
    const int qq = (i4 & 1) | (((i4 >> 3) & 1) << 1);
    const int g  = (i4 >> 1) & 3;
    const float sc = (p & 1) ? 0.5f : 1.0f;   // exact 2^-(p&1)
    #pragma unroll
    for (int d = 0; d < 4; ++d) {
        const int off = kk * 512 + g * 128 + (j0 + d) * 4 + qq;
        wsu[off] = pk_rtne(pr[d] * sc, pi[d] * sc);
    }
}

// ---------------- main chain kernel (31 pair-steps) ----------------
__global__ __launch_bounds__(256) void mps_pair16s_kernel(
    const int*   __restrict__ spin,
    const float* __restrict__ left_r,  const float* __restrict__ left_i,
    const float* __restrict__ right_r, const float* __restrict__ right_i,
    const unsigned* __restrict__ ws,
    float2*      __restrict__ out)
{
    __shared__ unsigned Vst[2][16 * 36];   // [buf][e*36 + slot], slot 0..31
    __shared__ float2 red[16][8];
    __shared__ unsigned smask[16][2];

    const int tid  = threadIdx.x;
    const int l    = tid & 63;
    const int wid  = tid >> 6;            // 0..3
    const int nt   = wid >> 1;            // column half
    const int cg   = wid & 1;             // s2 value this wave owns
    const int lr16 = l & 15;
    const int lg   = l >> 4;
    const int jc   = nt * 16 + lr16;      // C column (j)
    const int qjc  = qperm(jc);
    const int e0   = blockIdx.x * 16;

    // ---- spin masks (16 elements) ----
    if (tid < 16) {
        const int* sp = spin + (size_t)(e0 + tid) * 64;
        unsigned a0 = 0, a1 = 0;
        #pragma unroll
        for (int k = 0; k < 32; ++k) a0 |= (unsigned)(sp[k] & 1) << k;
        #pragma unroll
        for (int k = 0; k < 32; ++k) a1 |= (unsigned)(sp[32 + k] & 1) << k;
        smask[tid][0] = a0; smask[tid][1] = a1;
    }

    // ---- init v = left[s0] as packed fp16 (q-permuted) ----
    {
        const int e  = tid & 15;
        const int j0 = (tid >> 4) * 2;    // 0..30
        const int s0 = spin[(size_t)(e0 + e) * 64] & 1;
        #pragma unroll
        for (int d = 0; d < 2; ++d) {
            const int j  = j0 + d;
            const int qj = qperm(j);
            Vst[0][e * 36 + qj] = pk_rtne(left_r[s0 * 32 + j], left_i[s0 * 32 + j]);
        }
    }

    // ---- issue pair-0 P-fragment loads: P[s1][kk] ----
    const unsigned* pbw = ws + (size_t)(2 * cg) * 1024 + lg * 128 + jc * 4;
    u32x4 PA[2][2], PB[2][2];
    #pragma unroll
    for (int s1 = 0; s1 < 2; ++s1)
        #pragma unroll
        for (int kk = 0; kk < 2; ++kk)
            PA[s1][kk] = *(const u32x4*)(pbw + s1 * 1024 + kk * 512);

    __syncthreads();

    // per-lane spin words for its 4 C-row elements (rows lg*4+r)
    unsigned em0[4], em1[4];
    #pragma unroll
    for (int r = 0; r < 4; ++r) {
        em0[r] = smask[lg * 4 + r][0];
        em1[r] = smask[lg * 4 + r][1];
    }

    auto step = [&](int t, const unsigned* Vin, unsigned* Vout,
                    u32x4 (&Pc)[2][2], u32x4 (&Pn)[2][2]) {
        // prefetch next pair's P fragments
        {
            int tn = t + 1; if (tn > 30) tn = 30;
            const unsigned* pb = ws + (size_t)tn * 4096 + (size_t)(2 * cg) * 1024
                               + lg * 128 + jc * 4;
            #pragma unroll
            for (int s1 = 0; s1 < 2; ++s1)
                #pragma unroll
                for (int kk = 0; kk < 2; ++kk)
                    Pn[s1][kk] = *(const u32x4*)(pb + s1 * 1024 + kk * 512);
        }

        // V fragment reads (2 x ds_read_b128)
        const unsigned* pv = Vin + lr16 * 36 + 4 * lg;
        u32x4 Vh0 = *(const u32x4*)(pv);
        u32x4 Vh1 = *(const u32x4*)(pv + 16);

        // derive V_r = (vr,-vi) and V_i = (vi,vr)
        u32x4 r_h0, r_h1, i_h0, i_h1;
        #pragma unroll
        for (int q = 0; q < 4; ++q) {
            r_h0[q] = Vh0[q] ^ 0x80000000u;
            r_h1[q] = Vh1[q] ^ 0x80000000u;
            i_h0[q] = __builtin_amdgcn_alignbit(Vh0[q], Vh0[q], 16);
            i_h1[q] = __builtin_amdgcn_alignbit(Vh1[q], Vh1[q], 16);
        }

        // 8 MFMAs: both s1-combos x 2 kk x {R,I}
        f32x4 aR0 = {0.f,0.f,0.f,0.f}, aI0 = {0.f,0.f,0.f,0.f};
        f32x4 aR1 = {0.f,0.f,0.f,0.f}, aI1 = {0.f,0.f,0.f,0.f};
        __builtin_amdgcn_s_setprio(1);
        aR0 = MFMAH(r_h0, Pc[0][0], aR0); aR0 = MFMAH(r_h1, Pc[0][1], aR0);
        aI0 = MFMAH(i_h0, Pc[0][0], aI0); aI0 = MFMAH(i_h1, Pc[0][1], aI0);
        aR1 = MFMAH(r_h0, Pc[1][0], aR1); aR1 = MFMAH(r_h1, Pc[1][1], aR1);
        aI1 = MFMAH(i_h0, Pc[1][0], aI1); aI1 = MFMAH(i_h1, Pc[1][1], aI1);
        __builtin_amdgcn_s_setprio(0);

        // spin select: s1 picks combo (cndmask), s2 picks writing wave
        const int bp1 = 2 * t + 1, bp2 = 2 * t + 2;
        #pragma unroll
        for (int r = 0; r < 4; ++r) {
            const unsigned w1 = (bp1 < 32) ? em0[r] : em1[r];
            const unsigned w2 = (bp2 < 32) ? em0[r] : em1[r];
            const int s1b = (int)((w1 >> (bp1 & 31)) & 1u);
            const int s2b = (int)((w2 >> (bp2 & 31)) & 1u);
            const float wr = s1b ? aR1[r] : aR0[r];
            const float wi = s1b ? aI1[r] : aI0[r];
            if (s2b == cg) {
                const int ee = lg * 4 + r;
                Vout[ee * 36 + qjc] = pk_rtne(wr, wi);
            }
        }
        __syncthreads();
    };

    #pragma unroll 1
    for (int tt = 0; tt < 15; ++tt) {
        step(2 * tt,     Vst[0], Vst[1], PA, PB);
        step(2 * tt + 1, Vst[1], Vst[0], PB, PA);
    }
    step(30, Vst[0], Vst[1], PA, PB);     // final (odd) step -> Vst[1]

    // ---- right contraction (V in Vst[1]); amp *= 2^15 (exact rescale) ----
    if (tid < 128) {
        const int e = tid & 15, jg = tid >> 4;    // jg 0..7
        const unsigned sR = (smask[e][1] >> 31) & 1u;
        const float* Rr = right_r + sR * 32;
        const float* Ri = right_i + sR * 32;
        float pr = 0.f, pi = 0.f;
        #pragma unroll
        for (int d = 0; d < 4; ++d) {
            const int j  = jg * 4 + d;
            const unsigned h = Vst[1][e * 36 + qperm(j)];
            const float vr = f16lo(h);
            const float vi = f16hi(h);
            pr += vr * Rr[j] - vi * Ri[j];
            pi += vr * Ri[j] + vi * Rr[j];
        }
        red[e][jg] = make_float2(pr, pi);
    }
    __syncthreads();
    if (tid < 16) {
        float2 a = red[tid][0];
        #pragma unroll
        for (int k = 1; k < 8; ++k) { a.x += red[tid][k].x; a.y += red[tid][k].y; }
        out[e0 + tid] = make_float2(a.x * 32768.0f, a.y * 32768.0f);
    }
}

// ---------------- fallback (round-4 kernel) if ws too small ----------------
typedef __attribute__((ext_vector_type(8))) short s16x8;
__device__ __forceinline__ unsigned cvt_pk_bf16(float lo, float hi) {
    unsigned r;
    asm("v_cvt_pk_bf16_f32 %0, %1, %2" : "=v"(r) : "v"(lo), "v"(hi));
    return r;
}
__device__ __forceinline__ float lo_f(unsigned h) { return __uint_as_float(h << 16); }
__device__ __forceinline__ float hi_f(unsigned h) { return __uint_as_float(h & 0xFFFF0000u); }
__device__ __forceinline__ s16x8 frg(u32x4 x) { return __builtin_bit_cast(s16x8, x); }
#define MFMA16(A, B, C) __builtin_amdgcn_mfma_f32_16x16x32_bf16(frg(A), frg(B), C, 0, 0, 0)

__global__ __launch_bounds__(256, 1) void mps_mfma_kernel_fb(
    const int*   __restrict__ spin,
    const float* __restrict__ left_r,  const float* __restrict__ left_i,
    const float* __restrict__ bulk_r,  const float* __restrict__ bulk_i,
    const float* __restrict__ right_r, const float* __restrict__ right_i,
    float2*      __restrict__ out)
{
    __shared__ unsigned short Bf[2][2][2][2][4][32][8];
    __shared__ float vT[2][64][33];
    __shared__ float2 red[32][8];
    __shared__ unsigned smask[32][2];

    const int tid  = threadIdx.x;
    const int l    = tid & 63;
    const int wid  = tid >> 6;
    const int mt   = wid >> 1;
    const int nt   = wid & 1;
    const int lr16 = l & 15;
    const int lg   = l >> 4;
    const int ve   = mt * 16 + lr16;
    const int jc   = nt * 16 + lr16;
    const int blk  = blockIdx.x;
    const int ccol = tid & 31;
    const int c0   = tid >> 5;

    auto convert = [&](int site, int buf) {
        const float* br = bulk_r + (size_t)site * 2048 + ccol;
        const float* bi = bulk_i + (size_t)site * 2048 + ccol;
        #pragma unroll
        for (int h = 0; h < 2; ++h) {
            const int c  = c0 + h * 8;
            const int s  = c >> 3;
            const int kk = (c >> 2) & 1;
            const int g  = c & 3;
            const int ub = kk * 16 + 2 * g;
            const float* R = br + s * 1024;
            const float* I = bi + s * 1024;
            float v0 = R[(ub + 0) * 32], v1 = I[(ub + 0) * 32];
            float v2 = R[(ub + 1) * 32], v3 = I[(ub + 1) * 32];
            float v4 = R[(ub + 8) * 32], v5 = I[(ub + 8) * 32];
            float v6 = R[(ub + 9) * 32], v7 = I[(ub + 9) * 32];
            unsigned h0 = cvt_pk_bf16(v0, v1), h1 = cvt_pk_bf16(v2, v3);
            unsigned h2 = cvt_pk_bf16(v4, v5), h3 = cvt_pk_bf16(v6, v7);
            unsigned l0 = cvt_pk_bf16(v0 - lo_f(h0), v1 - hi_f(h0));
            unsigned l1 = cvt_pk_bf16(v2 - lo_f(h1), v3 - hi_f(h1));
            unsigned l2 = cvt_pk_bf16(v4 - lo_f(h2), v5 - hi_f(h2));
            unsigned l3 = cvt_pk_bf16(v6 - lo_f(h3), v7 - hi_f(h3));
            *(u32x4*)&Bf[buf][0][s][kk][g][ccol][0] = (u32x4){h0, h1, h2, h3};
            *(u32x4*)&Bf[buf][1][s][kk][g][ccol][0] = (u32x4){l0, l1, l2, l3};
        }
    };

    if (tid < 32) {
        const int* sp = spin + ((size_t)(blk * 32 + tid)) * 64;
        unsigned a0 = 0, a1 = 0;
        #pragma unroll
        for (int k = 0; k < 32; ++k) a0 |= (unsigned)(sp[k] & 1) << k;
        #pragma unroll
        for (int k = 0; k < 32; ++k) a1 |= (unsigned)(sp[32 + k] & 1) << k;
        smask[tid][0] = a0; smask[tid][1] = a1;
    }
    {
        const int e = tid & 31, jg = tid >> 5;
        const int s0 = spin[((size_t)(blk * 32 + e)) * 64] & 1;
        #pragma unroll
        for (int d = 0; d < 4; ++d) {
            const int j = jg * 4 + d;
            vT[0][2 * j    ][e] = left_r[s0 * 32 + j];
            vT[0][2 * j + 1][e] = left_i[s0 * 32 + j];
        }
    }
    convert(0, 0);
    __syncthreads();

    unsigned em0[4], em1[4];
    #pragma unroll
    for (int r = 0; r < 4; ++r) {
        const int ee = mt * 16 + lg * 4 + r;
        em0[r] = smask[ee][0];
        em1[r] = smask[ee][1];
    }

    #pragma unroll 2
    for (int t = 0; t < 62; ++t) {
        const int b = t & 1;
        float f[16];
        #pragma unroll
        for (int kk = 0; kk < 2; ++kk)
            #pragma unroll
            for (int q = 0; q < 2; ++q)
                #pragma unroll
                for (int r = 0; r < 4; ++r)
                    f[kk * 8 + q * 4 + r] = vT[b][kk * 32 + q * 16 + 4 * lg + r][ve];

        u32x4 Vh[2], Vl[2];
        #pragma unroll
        for (int kk = 0; kk < 2; ++kk)
            #pragma unroll
            for (int q = 0; q < 2; ++q) {
                const float a = f[kk*8+q*4+0], c2 = f[kk*8+q*4+1];
                const float d2 = f[kk*8+q*4+2], e2 = f[kk*8+q*4+3];
                const unsigned h0 = cvt_pk_bf16(a, c2);
                const unsigned h1 = cvt_pk_bf16(d2, e2);
                Vh[kk][q*2+0] = h0;
                Vh[kk][q*2+1] = h1;
                Vl[kk][q*2+0] = cvt_pk_bf16(a - lo_f(h0), c2 - hi_f(h0));
                Vl[kk][q*2+1] = cvt_pk_bf16(d2 - lo_f(h1), e2 - hi_f(h1));
            }

        u32x4 Bh[2][2], Bl[2][2];
        #pragma unroll
        for (int s = 0; s < 2; ++s)
            #pragma unroll
            for (int kk = 0; kk < 2; ++kk) {
                Bh[s][kk] = *(const u32x4*)&Bf[b][0][s][kk][lg][jc][0];
                Bl[s][kk] = *(const u32x4*)&Bf[b][1][s][kk][lg][jc][0];
            }

        if (t < 61) convert(t + 1, b ^ 1);

        f32x4 ar[2] = {{0,0,0,0},{0,0,0,0}};
        f32x4 ai[2] = {{0,0,0,0},{0,0,0,0}};
        #pragma unroll
        for (int kk = 0; kk < 2; ++kk) {
            u32x4 vh, vl;
            #pragma unroll
            for (int q = 0; q < 4; ++q) {
                vh[q] = Vh[kk][q] ^ 0x80000000u;
                vl[q] = Vl[kk][q] ^ 0x80000000u;
            }
            #pragma unroll
            for (int s = 0; s < 2; ++s) {
                ar[s] = MFMA16(vh, Bh[s][kk], ar[s]);
                ar[s] = MFMA16(vh, Bl[s][kk], ar[s]);
                ar[s] = MFMA16(vl, Bh[s][kk], ar[s]);
            }
        }
        #pragma unroll
        for (int kk = 0; kk < 2; ++kk) {
            u32x4 vh, vl;
            #pragma unroll
            for (int q = 0; q < 4; ++q) {
                vh[q] = __builtin_amdgcn_alignbit(Vh[kk][q], Vh[kk][q], 16);
                vl[q] = __builtin_amdgcn_alignbit(Vl[kk][q], Vl[kk][q], 16);
            }
            #pragma unroll
            for (int s = 0; s < 2; ++s) {
                ai[s] = MFMA16(vh, Bh[s][kk], ai[s]);
                ai[s] = MFMA16(vh, Bl[s][kk], ai[s]);
                ai[s] = MFMA16(vl, Bh[s][kk], ai[s]);
            }
        }

        const int bp = t + 1;
        #pragma unroll
        for (int r = 0; r < 4; ++r) {
            const unsigned mw = (bp < 32) ? em0[r] : em1[r];
            const bool sb = (mw >> (bp & 31)) & 1u;
            const int ee = mt * 16 + lg * 4 + r;
            vT[b ^ 1][2 * jc    ][ee] = sb ? ar[1][r] : ar[0][r];
            vT[b ^ 1][2 * jc + 1][ee] = sb ? ai[1][r] : ai[0][r];
        }
        __syncthreads();
    }

    {
        const int e = tid & 31, jg = tid >> 5;
        const unsigned sR = (smask[e][1] >> 31) & 1u;
        const float* Rr = right_r + sR * 32;
        const float* Ri = right_i + sR * 32;
        float pr = 0.f, pi = 0.f;
        #pragma unroll
        for (int d = 0; d < 4; ++d) {
            const int j = jg * 4 + d;
            const float vr = vT[0][2 * j][e], vi = vT[0][2 * j + 1][e];
            pr += vr * Rr[j] - vi * Ri[j];
            pi += vr * Ri[j] + vi * Rr[j];
        }
        red[e][jg] = make_float2(pr, pi);
    }
    __syncthreads();
    if (tid < 32) {
        float2 a = red[tid][0];
        #pragma unroll
        for (int k = 1; k < 8; ++k) { a.x += red[tid][k].x; a.y += red[tid][k].y; }
        out[blk * 32 + tid] = a;
    }
}

extern "C" void kernel_launch(void* const* d_in, const int* in_sizes, int n_in,
                              void* d_out, int out_size, void* d_ws, size_t ws_size,
                              hipStream_t stream)
{
    const int*   spin = (const int*)  d_in[0];
    const float* lr   = (const float*)d_in[1];
    const float* li   = (const float*)d_in[2];
    const float* br   = (const float*)d_in[3];
    const float* bi   = (const float*)d_in[4];
    const float* rr   = (const float*)d_in[5];
    const float* ri   = (const float*)d_in[6];
    float2* out = (float2*)d_out;

    const size_t WS_NEEDED = (size_t)31 * 16384;   // 496 KB
    if (ws_size >= WS_NEEDED) {
        unsigned* ws = (unsigned*)d_ws;
        mps_pairbuild<<<dim3(124), dim3(256), 0, stream>>>(br, bi, ws);
        mps_pair16s_kernel<<<dim3(512), dim3(256), 0, stream>>>(spin, lr, li, rr, ri, ws, out);
    } else {
        mps_mfma_kernel_fb<<<dim3(256), dim3(256), 0, stream>>>(spin, lr, li, br, bi, rr, ri, out);
    }
}

// Round 14
// 27.841 us; speedup vs baseline: 3.2212x; 1.0265x over previous
//
#include <hip/hip_runtime.h>
#include <stdint.h>

// MPS amplitude via MFMA, round 14: R13 minus per-step fixed costs.
// Delta vs R13 (proven 28.6us, absmax 256): (1) s_setprio removed (m190:
// setprio serializes lockstepped blocks sharing a CU); (2) step barriers are
// lgkm-only (s_waitcnt lgkmcnt(0) + s_barrier + sched_barrier(0) — R6's
// proven sequence) instead of __syncthreads()'s vmcnt(0) drain.
// Everything else identical: fp16 1-term P and V (RTNE), pair products with
// exact 2^-(p&1) scaling (epilogue x 2^15), 512 blocks x 256 thr, 31 steps.

typedef __attribute__((ext_vector_type(4))) float        f32x4;
typedef __attribute__((ext_vector_type(8))) _Float16     f16x8;
typedef __attribute__((ext_vector_type(4))) unsigned int u32x4;

__device__ __forceinline__ float f16lo(unsigned u) {
    return (float)__builtin_bit_cast(_Float16, (unsigned short)(u & 0xFFFFu));
}
__device__ __forceinline__ float f16hi(unsigned u) {
    return (float)__builtin_bit_cast(_Float16, (unsigned short)(u >> 16));
}
__device__ __forceinline__ unsigned pk_rtne(float a, float b) {
    unsigned short x = __builtin_bit_cast(unsigned short, (_Float16)a);
    unsigned short y = __builtin_bit_cast(unsigned short, (_Float16)b);
    return (unsigned)x | ((unsigned)y << 16);
}
__device__ __forceinline__ f16x8 frg16(u32x4 x) { return __builtin_bit_cast(f16x8, x); }
#define MFMAH(A, B, C) __builtin_amdgcn_mfma_f32_16x16x32_f16(frg16(A), frg16(B), C, 0, 0, 0)

// storage permutation: complex column u -> fragment word slot
__device__ __forceinline__ int qperm(int u) {
    return (u >> 4) * 16 + ((u >> 1) & 3) * 4 + ((u >> 3) & 1) * 2 + (u & 1);
}

// ---------------- pair-product build (one-time, 124 blocks) ----------------
// ws (u32 words): pair stride 4096 (16KB). word at p*4096 + c*1024 + off,
// off = kk*512 + g*128 + col*4 + q, matrix row i = kk*16 + 2g + (q&1) + 8*(q>>1).
__global__ __launch_bounds__(256, 1) void mps_pairbuild(
    const float* __restrict__ bulk_r, const float* __restrict__ bulk_i,
    unsigned* __restrict__ ws)
{
    const int bx = blockIdx.x;
    const int p  = bx >> 2;            // pair 0..30
    const int c  = bx & 3;             // combo = s1 + 2*s2
    const int s1 = c & 1, s2 = c >> 1;
    const float* A1r = bulk_r + ((size_t)(2 * p)     * 2 + s1) * 1024;
    const float* A1i = bulk_i + ((size_t)(2 * p)     * 2 + s1) * 1024;
    const float* A2r = bulk_r + ((size_t)(2 * p + 1) * 2 + s2) * 1024;
    const float* A2i = bulk_i + ((size_t)(2 * p + 1) * 2 + s2) * 1024;

    __shared__ float s1r[1024], s1i[1024], s2r[1024], s2i[1024];
    for (int k = threadIdx.x; k < 1024; k += 256) {
        s1r[k] = A1r[k]; s1i[k] = A1i[k];
        s2r[k] = A2r[k]; s2i[k] = A2i[k];
    }
    __syncthreads();

    const int i  = threadIdx.x >> 3;        // P row 0..31
    const int j0 = (threadIdx.x & 7) * 4;   // 4 output columns
    float pr[4] = {0,0,0,0}, pi[4] = {0,0,0,0};
    #pragma unroll 4
    for (int k = 0; k < 32; ++k) {
        const float ar = s1r[i * 32 + k], ai = s1i[i * 32 + k];
        #pragma unroll
        for (int d = 0; d < 4; ++d) {
            const float br = s2r[k * 32 + j0 + d], bi = s2i[k * 32 + j0 + d];
            pr[d] += ar * br - ai * bi;
            pi[d] += ar * bi + ai * br;
        }
    }

    unsigned* wsu = ws + (size_t)p * 4096 + (size_t)c * 1024;
    const int kk = i >> 4;
    const int i4 = i & 15;
    const int qq = (i4 & 1) | (((i4 >> 3) & 1) << 1);
    const int g  = (i4 >> 1) & 3;
    const float sc = (p & 1) ? 0.5f : 1.0f;   // exact 2^-(p&1)
    #pragma unroll
    for (int d = 0; d < 4; ++d) {
        const int off = kk * 512 + g * 128 + (j0 + d) * 4 + qq;
        wsu[off] = pk_rtne(pr[d] * sc, pi[d] * sc);
    }
}

// ---------------- main chain kernel (31 pair-steps) ----------------
__global__ __launch_bounds__(256) void mps_pair16t_kernel(
    const int*   __restrict__ spin,
    const float* __restrict__ left_r,  const float* __restrict__ left_i,
    const float* __restrict__ right_r, const float* __restrict__ right_i,
    const unsigned* __restrict__ ws,
    float2*      __restrict__ out)
{
    __shared__ unsigned Vst[2][16 * 36];   // [buf][e*36 + slot], slot 0..31
    __shared__ float2 red[16][8];
    __shared__ unsigned smask[16][2];

    const int tid  = threadIdx.x;
    const int l    = tid & 63;
    const int wid  = tid >> 6;            // 0..3
    const int nt   = wid >> 1;            // column half
    const int cg   = wid & 1;             // s2 value this wave owns
    const int lr16 = l & 15;
    const int lg   = l >> 4;
    const int jc   = nt * 16 + lr16;      // C column (j)
    const int qjc  = qperm(jc);
    const int e0   = blockIdx.x * 16;

    // ---- spin masks (16 elements) ----
    if (tid < 16) {
        const int* sp = spin + (size_t)(e0 + tid) * 64;
        unsigned a0 = 0, a1 = 0;
        #pragma unroll
        for (int k = 0; k < 32; ++k) a0 |= (unsigned)(sp[k] & 1) << k;
        #pragma unroll
        for (int k = 0; k < 32; ++k) a1 |= (unsigned)(sp[32 + k] & 1) << k;
        smask[tid][0] = a0; smask[tid][1] = a1;
    }

    // ---- init v = left[s0] as packed fp16 (q-permuted) ----
    {
        const int e  = tid & 15;
        const int j0 = (tid >> 4) * 2;    // 0..30
        const int s0 = spin[(size_t)(e0 + e) * 64] & 1;
        #pragma unroll
        for (int d = 0; d < 2; ++d) {
            const int j  = j0 + d;
            const int qj = qperm(j);
            Vst[0][e * 36 + qj] = pk_rtne(left_r[s0 * 32 + j], left_i[s0 * 32 + j]);
        }
    }

    // ---- issue pair-0 P-fragment loads: P[s1][kk] ----
    const unsigned* pbw = ws + (size_t)(2 * cg) * 1024 + lg * 128 + jc * 4;
    u32x4 PA[2][2], PB[2][2];
    #pragma unroll
    for (int s1 = 0; s1 < 2; ++s1)
        #pragma unroll
        for (int kk = 0; kk < 2; ++kk)
            PA[s1][kk] = *(const u32x4*)(pbw + s1 * 1024 + kk * 512);

    __syncthreads();

    // per-lane spin words for its 4 C-row elements (rows lg*4+r)
    unsigned em0[4], em1[4];
    #pragma unroll
    for (int r = 0; r < 4; ++r) {
        em0[r] = smask[lg * 4 + r][0];
        em1[r] = smask[lg * 4 + r][1];
    }

    auto step = [&](int t, const unsigned* Vin, unsigned* Vout,
                    u32x4 (&Pc)[2][2], u32x4 (&Pn)[2][2]) {
        // prefetch next pair's P fragments (may stay in flight across barrier)
        {
            int tn = t + 1; if (tn > 30) tn = 30;
            const unsigned* pb = ws + (size_t)tn * 4096 + (size_t)(2 * cg) * 1024
                               + lg * 128 + jc * 4;
            #pragma unroll
            for (int s1 = 0; s1 < 2; ++s1)
                #pragma unroll
                for (int kk = 0; kk < 2; ++kk)
                    Pn[s1][kk] = *(const u32x4*)(pb + s1 * 1024 + kk * 512);
        }

        // V fragment reads (2 x ds_read_b128)
        const unsigned* pv = Vin + lr16 * 36 + 4 * lg;
        u32x4 Vh0 = *(const u32x4*)(pv);
        u32x4 Vh1 = *(const u32x4*)(pv + 16);

        // derive V_r = (vr,-vi) and V_i = (vi,vr)
        u32x4 r_h0, r_h1, i_h0, i_h1;
        #pragma unroll
        for (int q = 0; q < 4; ++q) {
            r_h0[q] = Vh0[q] ^ 0x80000000u;
            r_h1[q] = Vh1[q] ^ 0x80000000u;
            i_h0[q] = __builtin_amdgcn_alignbit(Vh0[q], Vh0[q], 16);
            i_h1[q] = __builtin_amdgcn_alignbit(Vh1[q], Vh1[q], 16);
        }

        // 8 MFMAs: both s1-combos x 2 kk x {R,I}
        f32x4 aR0 = {0.f,0.f,0.f,0.f}, aI0 = {0.f,0.f,0.f,0.f};
        f32x4 aR1 = {0.f,0.f,0.f,0.f}, aI1 = {0.f,0.f,0.f,0.f};
        aR0 = MFMAH(r_h0, Pc[0][0], aR0); aR0 = MFMAH(r_h1, Pc[0][1], aR0);
        aI0 = MFMAH(i_h0, Pc[0][0], aI0); aI0 = MFMAH(i_h1, Pc[0][1], aI0);
        aR1 = MFMAH(r_h0, Pc[1][0], aR1); aR1 = MFMAH(r_h1, Pc[1][1], aR1);
        aI1 = MFMAH(i_h0, Pc[1][0], aI1); aI1 = MFMAH(i_h1, Pc[1][1], aI1);

        // spin select: s1 picks combo (cndmask), s2 picks writing wave
        const int bp1 = 2 * t + 1, bp2 = 2 * t + 2;
        #pragma unroll
        for (int r = 0; r < 4; ++r) {
            const unsigned w1 = (bp1 < 32) ? em0[r] : em1[r];
            const unsigned w2 = (bp2 < 32) ? em0[r] : em1[r];
            const int s1b = (int)((w1 >> (bp1 & 31)) & 1u);
            const int s2b = (int)((w2 >> (bp2 & 31)) & 1u);
            const float wr = s1b ? aR1[r] : aR0[r];
            const float wi = s1b ? aI1[r] : aI0[r];
            if (s2b == cg) {
                const int ee = lg * 4 + r;
                Vout[ee * 36 + qjc] = pk_rtne(wr, wi);
            }
        }
        // lgkm-only barrier: v exchange visible; VMEM stays in flight
        asm volatile("s_waitcnt lgkmcnt(0)" ::: "memory");
        __builtin_amdgcn_s_barrier();
        __builtin_amdgcn_sched_barrier(0);
    };

    #pragma unroll 1
    for (int tt = 0; tt < 15; ++tt) {
        step(2 * tt,     Vst[0], Vst[1], PA, PB);
        step(2 * tt + 1, Vst[1], Vst[0], PB, PA);
    }
    step(30, Vst[0], Vst[1], PA, PB);     // final (odd) step -> Vst[1]

    // ---- right contraction (V in Vst[1]); amp *= 2^15 (exact rescale) ----
    if (tid < 128) {
        const int e = tid & 15, jg = tid >> 4;    // jg 0..7
        const unsigned sR = (smask[e][1] >> 31) & 1u;
        const float* Rr = right_r + sR * 32;
        const float* Ri = right_i + sR * 32;
        float pr = 0.f, pi = 0.f;
        #pragma unroll
        for (int d = 0; d < 4; ++d) {
            const int j  = jg * 4 + d;
            const unsigned h = Vst[1][e * 36 + qperm(j)];
            const float vr = f16lo(h);
            const float vi = f16hi(h);
            pr += vr * Rr[j] - vi * Ri[j];
            pi += vr * Ri[j] + vi * Rr[j];
        }
        red[e][jg] = make_float2(pr, pi);
    }
    __syncthreads();
    if (tid < 16) {
        float2 a = red[tid][0];
        #pragma unroll
        for (int k = 1; k < 8; ++k) { a.x += red[tid][k].x; a.y += red[tid][k].y; }
        out[e0 + tid] = make_float2(a.x * 32768.0f, a.y * 32768.0f);
    }
}

// ---------------- fallback (round-4 kernel) if ws too small ----------------
typedef __attribute__((ext_vector_type(8))) short s16x8;
__device__ __forceinline__ unsigned cvt_pk_bf16(float lo, float hi) {
    unsigned r;
    asm("v_cvt_pk_bf16_f32 %0, %1, %2" : "=v"(r) : "v"(lo), "v"(hi));
    return r;
}
__device__ __forceinline__ float lo_f(unsigned h) { return __uint_as_float(h << 16); }
__device__ __forceinline__ float hi_f(unsigned h) { return __uint_as_float(h & 0xFFFF0000u); }
__device__ __forceinline__ s16x8 frg(u32x4 x) { return __builtin_bit_cast(s16x8, x); }
#define MFMA16(A, B, C) __builtin_amdgcn_mfma_f32_16x16x32_bf16(frg(A), frg(B), C, 0, 0, 0)

__global__ __launch_bounds__(256, 1) void mps_mfma_kernel_fb(
    const int*   __restrict__ spin,
    const float* __restrict__ left_r,  const float* __restrict__ left_i,
    const float* __restrict__ bulk_r,  const float* __restrict__ bulk_i,
    const float* __restrict__ right_r, const float* __restrict__ right_i,
    float2*      __restrict__ out)
{
    __shared__ unsigned short Bf[2][2][2][2][4][32][8];
    __shared__ float vT[2][64][33];
    __shared__ float2 red[32][8];
    __shared__ unsigned smask[32][2];

    const int tid  = threadIdx.x;
    const int l    = tid & 63;
    const int wid  = tid >> 6;
    const int mt   = wid >> 1;
    const int nt   = wid & 1;
    const int lr16 = l & 15;
    const int lg   = l >> 4;
    const int ve   = mt * 16 + lr16;
    const int jc   = nt * 16 + lr16;
    const int blk  = blockIdx.x;
    const int ccol = tid & 31;
    const int c0   = tid >> 5;

    auto convert = [&](int site, int buf) {
        const float* br = bulk_r + (size_t)site * 2048 + ccol;
        const float* bi = bulk_i + (size_t)site * 2048 + ccol;
        #pragma unroll
        for (int h = 0; h < 2; ++h) {
            const int c  = c0 + h * 8;
            const int s  = c >> 3;
            const int kk = (c >> 2) & 1;
            const int g  = c & 3;
            const int ub = kk * 16 + 2 * g;
            const float* R = br + s * 1024;
            const float* I = bi + s * 1024;
            float v0 = R[(ub + 0) * 32], v1 = I[(ub + 0) * 32];
            float v2 = R[(ub + 1) * 32], v3 = I[(ub + 1) * 32];
            float v4 = R[(ub + 8) * 32], v5 = I[(ub + 8) * 32];
            float v6 = R[(ub + 9) * 32], v7 = I[(ub + 9) * 32];
            unsigned h0 = cvt_pk_bf16(v0, v1), h1 = cvt_pk_bf16(v2, v3);
            unsigned h2 = cvt_pk_bf16(v4, v5), h3 = cvt_pk_bf16(v6, v7);
            unsigned l0 = cvt_pk_bf16(v0 - lo_f(h0), v1 - hi_f(h0));
            unsigned l1 = cvt_pk_bf16(v2 - lo_f(h1), v3 - hi_f(h1));
            unsigned l2 = cvt_pk_bf16(v4 - lo_f(h2), v5 - hi_f(h2));
            unsigned l3 = cvt_pk_bf16(v6 - lo_f(h3), v7 - hi_f(h3));
            *(u32x4*)&Bf[buf][0][s][kk][g][ccol][0] = (u32x4){h0, h1, h2, h3};
            *(u32x4*)&Bf[buf][1][s][kk][g][ccol][0] = (u32x4){l0, l1, l2, l3};
        }
    };

    if (tid < 32) {
        const int* sp = spin + ((size_t)(blk * 32 + tid)) * 64;
        unsigned a0 = 0, a1 = 0;
        #pragma unroll
        for (int k = 0; k < 32; ++k) a0 |= (unsigned)(sp[k] & 1) << k;
        #pragma unroll
        for (int k = 0; k < 32; ++k) a1 |= (unsigned)(sp[32 + k] & 1) << k;
        smask[tid][0] = a0; smask[tid][1] = a1;
    }
    {
        const int e = tid & 31, jg = tid >> 5;
        const int s0 = spin[((size_t)(blk * 32 + e)) * 64] & 1;
        #pragma unroll
        for (int d = 0; d < 4; ++d) {
            const int j = jg * 4 + d;
            vT[0][2 * j    ][e] = left_r[s0 * 32 + j];
            vT[0][2 * j + 1][e] = left_i[s0 * 32 + j];
        }
    }
    convert(0, 0);
    __syncthreads();

    unsigned em0[4], em1[4];
    #pragma unroll
    for (int r = 0; r < 4; ++r) {
        const int ee = mt * 16 + lg * 4 + r;
        em0[r] = smask[ee][0];
        em1[r] = smask[ee][1];
    }

    #pragma unroll 2
    for (int t = 0; t < 62; ++t) {
        const int b = t & 1;
        float f[16];
        #pragma unroll
        for (int kk = 0; kk < 2; ++kk)
            #pragma unroll
            for (int q = 0; q < 2; ++q)
                #pragma unroll
                for (int r = 0; r < 4; ++r)
                    f[kk * 8 + q * 4 + r] = vT[b][kk * 32 + q * 16 + 4 * lg + r][ve];

        u32x4 Vh[2], Vl[2];
        #pragma unroll
        for (int kk = 0; kk < 2; ++kk)
            #pragma unroll
            for (int q = 0; q < 2; ++q) {
                const float a = f[kk*8+q*4+0], c2 = f[kk*8+q*4+1];
                const float d2 = f[kk*8+q*4+2], e2 = f[kk*8+q*4+3];
                const unsigned h0 = cvt_pk_bf16(a, c2);
                const unsigned h1 = cvt_pk_bf16(d2, e2);
                Vh[kk][q*2+0] = h0;
                Vh[kk][q*2+1] = h1;
                Vl[kk][q*2+0] = cvt_pk_bf16(a - lo_f(h0), c2 - hi_f(h0));
                Vl[kk][q*2+1] = cvt_pk_bf16(d2 - lo_f(h1), e2 - hi_f(h1));
            }

        u32x4 Bh[2][2], Bl[2][2];
        #pragma unroll
        for (int s = 0; s < 2; ++s)
            #pragma unroll
            for (int kk = 0; kk < 2; ++kk) {
                Bh[s][kk] = *(const u32x4*)&Bf[b][0][s][kk][lg][jc][0];
                Bl[s][kk] = *(const u32x4*)&Bf[b][1][s][kk][lg][jc][0];
            }

        if (t < 61) convert(t + 1, b ^ 1);

        f32x4 ar[2] = {{0,0,0,0},{0,0,0,0}};
        f32x4 ai[2] = {{0,0,0,0},{0,0,0,0}};
        #pragma unroll
        for (int kk = 0; kk < 2; ++kk) {
            u32x4 vh, vl;
            #pragma unroll
            for (int q = 0; q < 4; ++q) {
                vh[q] = Vh[kk][q] ^ 0x80000000u;
                vl[q] = Vl[kk][q] ^ 0x80000000u;
            }
            #pragma unroll
            for (int s = 0; s < 2; ++s) {
                ar[s] = MFMA16(vh, Bh[s][kk], ar[s]);
                ar[s] = MFMA16(vh, Bl[s][kk], ar[s]);
                ar[s] = MFMA16(vl, Bh[s][kk], ar[s]);
            }
        }
        #pragma unroll
        for (int kk = 0; kk < 2; ++kk) {
            u32x4 vh, vl;
            #pragma unroll
            for (int q = 0; q < 4; ++q) {
                vh[q] = __builtin_amdgcn_alignbit(Vh[kk][q], Vh[kk][q], 16);
                vl[q] = __builtin_amdgcn_alignbit(Vl[kk][q], Vl[kk][q], 16);
            }
            #pragma unroll
            for (int s = 0; s < 2; ++s) {
                ai[s] = MFMA16(vh, Bh[s][kk], ai[s]);
                ai[s] = MFMA16(vh, Bl[s][kk], ai[s]);
                ai[s] = MFMA16(vl, Bh[s][kk], ai[s]);
            }
        }

        const int bp = t + 1;
        #pragma unroll
        for (int r = 0; r < 4; ++r) {
            const unsigned mw = (bp < 32) ? em0[r] : em1[r];
            const bool sb = (mw >> (bp & 31)) & 1u;
            const int ee = mt * 16 + lg * 4 + r;
            vT[b ^ 1][2 * jc    ][ee] = sb ? ar[1][r] : ar[0][r];
            vT[b ^ 1][2 * jc + 1][ee] = sb ? ai[1][r] : ai[0][r];
        }
        __syncthreads();
    }

    {
        const int e = tid & 31, jg = tid >> 5;
        const unsigned sR = (smask[e][1] >> 31) & 1u;
        const float* Rr = right_r + sR * 32;
        const float* Ri = right_i + sR * 32;
        float pr = 0.f, pi = 0.f;
        #pragma unroll
        for (int d = 0; d < 4; ++d) {
            const int j = jg * 4 + d;
            const float vr = vT[0][2 * j][e], vi = vT[0][2 * j + 1][e];
            pr += vr * Rr[j] - vi * Ri[j];
            pi += vr * Ri[j] + vi * Rr[j];
        }
        red[e][jg] = make_float2(pr, pi);
    }
    __syncthreads();
    if (tid < 32) {
        float2 a = red[tid][0];
        #pragma unroll
        for (int k = 1; k < 8; ++k) { a.x += red[tid][k].x; a.y += red[tid][k].y; }
        out[blk * 32 + tid] = a;
    }
}

extern "C" void kernel_launch(void* const* d_in, const int* in_sizes, int n_in,
                              void* d_out, int out_size, void* d_ws, size_t ws_size,
                              hipStream_t stream)
{
    const int*   spin = (const int*)  d_in[0];
    const float* lr   = (const float*)d_in[1];
    const float* li   = (const float*)d_in[2];
    const float* br   = (const float*)d_in[3];
    const float* bi   = (const float*)d_in[4];
    const float* rr   = (const float*)d_in[5];
    const float* ri   = (const float*)d_in[6];
    float2* out = (float2*)d_out;

    const size_t WS_NEEDED = (size_t)31 * 16384;   // 496 KB
    if (ws_size >= WS_NEEDED) {
        unsigned* ws = (unsigned*)d_ws;
        mps_pairbuild<<<dim3(124), dim3(256), 0, stream>>>(br, bi, ws);
        mps_pair16t_kernel<<<dim3(512), dim3(256), 0, stream>>>(spin, lr, li, rr, ri, ws, out);
    } else {
        mps_mfma_kernel_fb<<<dim3(256), dim3(256), 0, stream>>>(spin, lr, li, br, bi, rr, ri, out);
    }
}